// Round 11
// baseline (575.266 us; speedup 1.0000x reference)
//
#include <hip/hip_runtime.h>
#include <stdint.h>

#define NN 100000
#define NE 1600000
#define NFLAT 12800000u  // NN*128
#define XRANGE 12500     // NN / 8 nodes per XCD range
#define GBLK 782         // ceil(NN / 128) row-blocks for the GEMMs
#define MAXDEG 64        // Poisson(16): P(deg>64) ~ 1e-20
#define SEGSHIFT 12
#define SEGCAP 4096      // per (bucket,segment) capacity; mean 3125, +18 sigma
#define NSEG 64          // segments per bucket (indexed by blockIdx & 63)
#define SFBLK 128        // scatter blocks per bucket

typedef _Float16 f16;
typedef __attribute__((ext_vector_type(2))) _Float16 f16x2;
typedef __attribute__((ext_vector_type(4))) _Float16 f16x4;
typedef __attribute__((ext_vector_type(8))) _Float16 f16x8;
typedef __attribute__((ext_vector_type(4))) float f32x4;

// ---------------- threefry2x32 (JAX-compatible) ----------------
__device__ __forceinline__ uint32_t rotl32(uint32_t x, int r) {
  return __builtin_amdgcn_alignbit(x, x, (32 - r) & 31);
}

__device__ __forceinline__ void tf2x32(uint32_t k0, uint32_t k1,
                                       uint32_t x0, uint32_t x1,
                                       uint32_t &o0, uint32_t &o1) {
  uint32_t ks2 = k0 ^ k1 ^ 0x1BD11BDAu;
#define TF_R(r) { x0 += x1; x1 = rotl32(x1, r); x1 ^= x0; }
  x0 += k0; x1 += k1;
  TF_R(13) TF_R(15) TF_R(26) TF_R(6)
  x0 += k1;  x1 += ks2 + 1u;
  TF_R(17) TF_R(29) TF_R(16) TF_R(24)
  x0 += ks2; x1 += k0 + 2u;
  TF_R(13) TF_R(15) TF_R(26) TF_R(6)
  x0 += k0;  x1 += k1 + 3u;
  TF_R(17) TF_R(29) TF_R(16) TF_R(24)
  x0 += k1;  x1 += ks2 + 4u;
  TF_R(13) TF_R(15) TF_R(26) TF_R(6)
  x0 += ks2; x1 += k0 + 5u;
#undef TF_R
  o0 = x0; o1 = x1;
}

static void tf2x32_host(uint32_t k0, uint32_t k1, uint32_t x0, uint32_t x1,
                        uint32_t *o0, uint32_t *o1) {
  uint32_t ks2 = k0 ^ k1 ^ 0x1BD11BDAu;
#define TF_R(r) { x0 += x1; x1 = (x1 << (r)) | (x1 >> (32 - (r))); x1 ^= x0; }
  x0 += k0; x1 += k1;
  TF_R(13) TF_R(15) TF_R(26) TF_R(6)
  x0 += k1;  x1 += ks2 + 1u;
  TF_R(17) TF_R(29) TF_R(16) TF_R(24)
  x0 += ks2; x1 += k0 + 2u;
  TF_R(13) TF_R(15) TF_R(26) TF_R(6)
  x0 += k0;  x1 += k1 + 3u;
  TF_R(17) TF_R(29) TF_R(16) TF_R(24)
  x0 += k1;  x1 += ks2 + 4u;
  TF_R(13) TF_R(15) TF_R(26) TF_R(6)
  x0 += ks2; x1 += k0 + 5u;
#undef TF_R
  *o0 = x0; *o1 = x1;
}

// ---------------- phase A: bin edges, wave-ballot aggregated --------------
// Lane's bucket b = dst/XRANGE. Eight ballots give the lane its in-wave
// position and the wave's count per bucket (no LDS atomics). Group leaders
// (pos==0) reserve space with ONE global atomicAdd on a SEGMENTED counter
// bcnt[b*NSEG + (blockIdx&63)] -> 512 counters, ~390-deep chains instead of
// R10's 6250-deep on 8 counters (the measured 75 us serialization).
__global__ __launch_bounds__(256) void bin_edges(const int *__restrict__ src,
                                                 const int *__restrict__ dst,
                                                 int *__restrict__ bcnt,
                                                 int2 *__restrict__ pairs) {
  __shared__ int wbase[4][8];
  const int tid = threadIdx.x;
  const int lane = tid & 63;
  const int wv = tid >> 6;
  const int seg = blockIdx.x & (NSEG - 1);
  const int e = blockIdx.x * 256 + tid;  // NE == 6250*256 exactly
  const int d = dst[e];
  const int s = src[e];
  const int b = d / XRANGE;
  const unsigned long long lt = (1ULL << lane) - 1ULL;
  int pos = 0, wcnt = 0;
#pragma unroll
  for (int bb = 0; bb < 8; ++bb) {
    unsigned long long mk = __ballot(b == bb);
    if (b == bb) {
      pos = __popcll(mk & lt);
      wcnt = __popcll(mk);
    }
  }
  if (pos == 0) wbase[wv][b] = atomicAdd(&bcnt[b * NSEG + seg], wcnt);
  __syncthreads();
  int idx = wbase[wv][b] + pos;
  if (idx < SEGCAP)
    pairs[(size_t)(b * NSEG + seg) * SEGCAP + idx] = make_int2(d, s);
}

// ---------------- phase B: XCD-local scatter into fixed-stride slots ------
// Blocks bid&7 == x drain bucket x's 64 segments. Per XCD: ~2 MB sequential
// pair read (cannot pollute L2) + cursor atomics + col2 writes confined to
// its 3.2 MB L2-resident slice -> dirty lines accumulate ~16 writes each.
__global__ __launch_bounds__(256) void scatter_fill(const int2 *__restrict__ pairs,
                                                    const int *__restrict__ bcnt,
                                                    int *__restrict__ cursor,
                                                    int *__restrict__ col2) {
  const int x = blockIdx.x & 7;
  const int nb = blockIdx.x >> 3;
  const size_t base = (size_t)x * NSEG * SEGCAP;
  for (int i = nb * 256 + threadIdx.x; i < NSEG * SEGCAP; i += SFBLK * 256) {
    int seg = i >> SEGSHIFT;
    int off = i & (SEGCAP - 1);
    int cnt = bcnt[x * NSEG + seg];
    if (off < min(cnt, SEGCAP)) {
      int2 r = pairs[base + i];
      int p = atomicAdd(&cursor[r.x], 1);
      if (p < MAXDEG) col2[r.x * MAXDEG + p] = r.y;
    }
  }
}

// ---------------- conversions ----------------
__global__ __launch_bounds__(256) void cvt_x_kernel(const float *__restrict__ x,
                                                    f16 *__restrict__ xh) {
  uint32_t i = (blockIdx.x * 256 + threadIdx.x) * 4;
  float4 v = *(const float4 *)(x + i);
  f16x4 o;
  o[0] = (f16)v.x; o[1] = (f16)v.y; o[2] = (f16)v.z; o[3] = (f16)v.w;
  *(f16x4 *)(xh + i) = o;
}

// weights -> fp16, k-major: Wk[col][k] = W[k][col]
__global__ __launch_bounds__(256) void cvt_w_kernel(
    const float *__restrict__ w0, const float *__restrict__ w1,
    const float *__restrict__ w2, const float *__restrict__ lw,
    f16 *__restrict__ Wk0, f16 *__restrict__ Wk1, f16 *__restrict__ Wk2,
    f16 *__restrict__ WkL) {
  int t = blockIdx.x * 256 + threadIdx.x;
  if (t < 3 * 32768) {
    int wi = t >> 15, r = t & 32767;  // r = k*128 + c
    int k = r >> 7, c = r & 127;
    const float *w = (wi == 0) ? w0 : ((wi == 1) ? w1 : w2);
    f16 *o = (wi == 0) ? Wk0 : ((wi == 1) ? Wk1 : Wk2);
    o[c * 256 + k] = (f16)w[r];
  } else {
    int r = t - 3 * 32768;  // r = k*64 + c, r < 8192
    int k = r >> 6, c = r & 63;
    WkL[c * 128 + k] = (f16)lw[r];
  }
}

// ---------------- mean aggregation + fused dropout-mask gen ----------------
// One wave per node; slots at n*MAXDEG, degree from cursor (clamped).
__global__ __launch_bounds__(256) void agg_kernel(const f16 *__restrict__ h,
                                                  const int *__restrict__ deg,
                                                  const int *__restrict__ col2,
                                                  f16 *__restrict__ agg,
                                                  uint32_t *__restrict__ mrow,
                                                  uint32_t mk0, uint32_t mk1) {
  int wid = threadIdx.x >> 6;
  int lane = threadIdx.x & 63;
  int n = blockIdx.x * 4 + wid;
  if (n >= NN) return;

  // ---- fused mask (independent VALU work; hides under gather latency)
  {
    uint32_t j0 = (uint32_t)n * 128u + (uint32_t)lane;
    uint32_t o0, o1, p0, p1;
    tf2x32(mk0, mk1, 0u, j0, o0, o1);
    tf2x32(mk0, mk1, 0u, j0 + 64u, p0, p1);
    unsigned long long blo = __ballot((int)(o0 ^ o1) >= 0);
    unsigned long long bhi = __ballot((int)(p0 ^ p1) >= 0);
    if (lane == 0) {
      uint4 mv;
      mv.x = (uint32_t)blo; mv.y = (uint32_t)(blo >> 32);
      mv.z = (uint32_t)bhi; mv.w = (uint32_t)(bhi >> 32);
      *(uint4 *)(mrow + (size_t)n * 4) = mv;
    }
  }

  const int beg = n * MAXDEG;
  int d = min(deg[n], MAXDEG);
  const int half = lane >> 5;
  const int q = lane & 31;
  float s0 = 0.f, s1 = 0.f, s2 = 0.f, s3 = 0.f;
  int i = 0;
  for (; i + 8 <= d; i += 8) {
    int c0 = col2[beg + i + 0 + half];
    int c1 = col2[beg + i + 2 + half];
    int c2 = col2[beg + i + 4 + half];
    int c3 = col2[beg + i + 6 + half];
    f16x4 v0 = ((const f16x4 *)(h + (size_t)c0 * 128))[q];
    f16x4 v1 = ((const f16x4 *)(h + (size_t)c1 * 128))[q];
    f16x4 v2 = ((const f16x4 *)(h + (size_t)c2 * 128))[q];
    f16x4 v3 = ((const f16x4 *)(h + (size_t)c3 * 128))[q];
    s0 += (float)v0[0] + (float)v1[0] + (float)v2[0] + (float)v3[0];
    s1 += (float)v0[1] + (float)v1[1] + (float)v2[1] + (float)v3[1];
    s2 += (float)v0[2] + (float)v1[2] + (float)v2[2] + (float)v3[2];
    s3 += (float)v0[3] + (float)v1[3] + (float)v2[3] + (float)v3[3];
  }
  for (; i + 2 <= d; i += 2) {
    int c = col2[beg + i + half];
    f16x4 v = ((const f16x4 *)(h + (size_t)c * 128))[q];
    s0 += (float)v[0]; s1 += (float)v[1];
    s2 += (float)v[2]; s3 += (float)v[3];
  }
  if (i < d && half == 0) {
    int c = col2[beg + i];
    f16x4 v = ((const f16x4 *)(h + (size_t)c * 128))[q];
    s0 += (float)v[0]; s1 += (float)v[1];
    s2 += (float)v[2]; s3 += (float)v[3];
  }
  s0 += __shfl_xor(s0, 32);
  s1 += __shfl_xor(s1, 32);
  s2 += __shfl_xor(s2, 32);
  s3 += __shfl_xor(s3, 32);
  if (half == 0) {
    float inv = 1.0f / (float)max(d, 1);
    f16x4 o;
    o[0] = (f16)(s0 * inv); o[1] = (f16)(s1 * inv);
    o[2] = (f16)(s2 * inv); o[3] = (f16)(s3 * inv);
    ((f16x4 *)(agg + (size_t)n * 128))[q] = o;
  }
}

// ---------------- fused [agg,h]@W + b -> relu -> dropout (MFMA f16) --------
// B-stationary: wave wv owns output cols [wv*32, wv*32+32) as two 16-col
// tiles; its B fragments for all K=256 live in 64 VGPRs (loaded once).
__global__ __launch_bounds__(256) void sage_gemm_f16(
    const f16 *__restrict__ agg, const f16 *__restrict__ hin,
    const f16 *__restrict__ Wk, const float *__restrict__ bias,
    const uint32_t *__restrict__ mask, f16 *__restrict__ hout) {
  const int tid = threadIdx.x;
  const int lane = tid & 63;
  const int wv = tid >> 6;
  const int blk_row0 = blockIdx.x * 128;
  const int kg = (lane >> 4) * 8;
  const int col_lo = lane & 15;

  f16x8 Bf[2][8];
#pragma unroll
  for (int t = 0; t < 2; ++t) {
    const int colb = wv * 32 + t * 16 + col_lo;
#pragma unroll
    for (int ks = 0; ks < 8; ++ks)
      Bf[t][ks] = *(const f16x8 *)(Wk + (size_t)colb * 256 + ks * 32 + kg);
  }
  const float bv0 = bias[wv * 32 + col_lo];
  const float bv1 = bias[wv * 32 + 16 + col_lo];

#pragma unroll 2
  for (int s = 0; s < 8; ++s) {
    const int row0 = blk_row0 + s * 16;
    const int ar = row0 + col_lo;
    const bool rowok = ar < NN;
    f16x8 Af[8];
#pragma unroll
    for (int ks = 0; ks < 8; ++ks) {
      const f16 *asrc = (ks < 4)
                            ? (agg + (size_t)ar * 128 + ks * 32 + kg)
                            : (hin + (size_t)ar * 128 + (ks - 4) * 32 + kg);
      Af[ks] = rowok ? *(const f16x8 *)asrc : (f16x8){};
    }
    f32x4 acc0 = {0.f, 0.f, 0.f, 0.f}, acc1 = {0.f, 0.f, 0.f, 0.f};
#pragma unroll
    for (int ks = 0; ks < 8; ++ks) {
      acc0 = __builtin_amdgcn_mfma_f32_16x16x32_f16(Af[ks], Bf[0][ks], acc0, 0, 0, 0);
      acc1 = __builtin_amdgcn_mfma_f32_16x16x32_f16(Af[ks], Bf[1][ks], acc1, 0, 0, 0);
    }
    const int rbase = row0 + (lane >> 4) * 4;
    const int c0 = wv * 32 + col_lo;
    const int c1 = c0 + 16;
#pragma unroll
    for (int r = 0; r < 4; ++r) {
      const int row = rbase + r;
      if (row < NN) {
        uint32_t mw = mask[(size_t)row * 4 + wv];  // both tiles share word wv
        float z0 = acc0[r] + bv0;
        float z1 = acc1[r] + bv1;
        z0 = (z0 > 0.f && ((mw >> col_lo) & 1u)) ? z0 * 2.f : 0.f;
        z1 = (z1 > 0.f && ((mw >> (16 + col_lo)) & 1u)) ? z1 * 2.f : 0.f;
        hout[(size_t)row * 128 + c0] = (f16)z0;
        hout[(size_t)row * 128 + c1] = (f16)z1;
      }
    }
  }
}

// ---------------- final h @ lin_w + lin_b (MFMA f16, f32 out) ----------------
__global__ __launch_bounds__(256) void final_gemm_f16(
    const f16 *__restrict__ hin, const f16 *__restrict__ WkL,
    const float *__restrict__ bias, float *__restrict__ outp) {
  const int tid = threadIdx.x;
  const int lane = tid & 63;
  const int wv = tid >> 6;       // owns cols [wv*16, +16)
  const int blk_row0 = blockIdx.x * 128;
  const int kg = (lane >> 4) * 8;
  const int col_lo = lane & 15;
  const int c = wv * 16 + col_lo;
  f16x8 Bf[4];
#pragma unroll
  for (int ks = 0; ks < 4; ++ks)
    Bf[ks] = *(const f16x8 *)(WkL + (size_t)c * 128 + ks * 32 + kg);
  const float bv = bias[c];
#pragma unroll 2
  for (int s = 0; s < 8; ++s) {
    const int row0 = blk_row0 + s * 16;
    const int ar = row0 + col_lo;
    const bool rowok = ar < NN;
    f32x4 acc = {0.f, 0.f, 0.f, 0.f};
#pragma unroll
    for (int ks = 0; ks < 4; ++ks) {
      f16x8 a = rowok
                    ? *(const f16x8 *)(hin + (size_t)ar * 128 + ks * 32 + kg)
                    : (f16x8){};
      acc = __builtin_amdgcn_mfma_f32_16x16x32_f16(a, Bf[ks], acc, 0, 0, 0);
    }
    const int rbase = row0 + (lane >> 4) * 4;
#pragma unroll
    for (int r = 0; r < 4; ++r) {
      const int row = rbase + r;
      if (row < NN) outp[(size_t)row * 64 + c] = acc[r] + bv;
    }
  }
}

extern "C" void kernel_launch(void *const *d_in, const int *in_sizes, int n_in,
                              void *d_out, int out_size, void *d_ws,
                              size_t ws_size, hipStream_t stream) {
  (void)in_sizes; (void)n_in; (void)out_size; (void)ws_size;
  const float *x = (const float *)d_in[0];
  const int *edge = (const int *)d_in[1];
  const int *src = edge;
  const int *dst = edge + NE;
  const float *w0 = (const float *)d_in[2];
  const float *b0 = (const float *)d_in[3];
  const float *w1 = (const float *)d_in[4];
  const float *b1 = (const float *)d_in[5];
  const float *w2 = (const float *)d_in[6];
  const float *b2 = (const float *)d_in[7];
  const float *lw = (const float *)d_in[8];
  const float *lb = (const float *)d_in[9];
  float *out = (float *)d_out;

  char *ws = (char *)d_ws;
  f16 *xh  = (f16 *)ws; ws += (size_t)NN * 128 * 2;   // also reused as h3
  f16 *h1  = (f16 *)ws; ws += (size_t)NN * 128 * 2;
  f16 *h2  = (f16 *)ws; ws += (size_t)NN * 128 * 2;
  f16 *agg = (f16 *)ws; ws += (size_t)NN * 128 * 2;
  f16 *Wk0 = (f16 *)ws; ws += 256 * 128 * 2;
  f16 *Wk1 = (f16 *)ws; ws += 256 * 128 * 2;
  f16 *Wk2 = (f16 *)ws; ws += 256 * 128 * 2;
  f16 *WkL = (f16 *)ws; ws += 128 * 64 * 2;
  int *cursor = (int *)ws; ws += (size_t)NN * 4;
  int *col2 = (int *)ws;   ws += (size_t)NN * MAXDEG * 4;
  int *bcnt = (int *)ws;   ws += 8 * NSEG * 4;
  int2 *pairs = (int2 *)ws; ws += (size_t)8 * NSEG * SEGCAP * 8;
  uint32_t *m0 = (uint32_t *)ws; ws += (size_t)(NFLAT / 32) * 4;
  uint32_t *m1 = (uint32_t *)ws; ws += (size_t)(NFLAT / 32) * 4;
  uint32_t *m2 = (uint32_t *)ws; ws += (size_t)(NFLAT / 32) * 4;

  uint32_t fk[3][2];
  for (int i = 0; i < 3; ++i)
    tf2x32_host(0u, 42u, 0u, (uint32_t)i, &fk[i][0], &fk[i][1]);

  hipMemsetAsync(cursor, 0, (size_t)NN * 4, stream);
  hipMemsetAsync(bcnt, 0, 8 * NSEG * 4, stream);
  bin_edges<<<NE / 256, 256, 0, stream>>>(src, dst, bcnt, pairs);
  scatter_fill<<<8 * SFBLK, 256, 0, stream>>>(pairs, bcnt, cursor, col2);
  cvt_x_kernel<<<NFLAT / 1024, 256, 0, stream>>>(x, xh);
  cvt_w_kernel<<<416, 256, 0, stream>>>(w0, w1, w2, lw, Wk0, Wk1, Wk2, WkL);

  // layer 0 (agg also generates m0)
  agg_kernel<<<NN / 4, 256, 0, stream>>>(xh, cursor, col2, agg, m0,
                                         fk[0][0], fk[0][1]);
  sage_gemm_f16<<<GBLK, 256, 0, stream>>>(agg, xh, Wk0, b0, m0, h1);
  // layer 1 (agg also generates m1)
  agg_kernel<<<NN / 4, 256, 0, stream>>>(h1, cursor, col2, agg, m1,
                                         fk[1][0], fk[1][1]);
  sage_gemm_f16<<<GBLK, 256, 0, stream>>>(agg, h1, Wk1, b1, m1, h2);
  // layer 2 (agg also generates m2; output reuses xh buffer)
  agg_kernel<<<NN / 4, 256, 0, stream>>>(h2, cursor, col2, agg, m2,
                                         fk[2][0], fk[2][1]);
  sage_gemm_f16<<<GBLK, 256, 0, stream>>>(agg, h2, Wk2, b2, m2, xh);
  // final linear
  final_gemm_f16<<<GBLK, 256, 0, stream>>>(xh, WkL, lb, out);
}

// Round 12
// 472.560 us; speedup vs baseline: 1.2173x; 1.2173x over previous
//
#include <hip/hip_runtime.h>
#include <stdint.h>

#define NN 100000
#define NE 1600000
#define NFLAT 12800000u  // NN*128
#define XRANGE 12500     // NN / 8 nodes per XCD range
#define XCHUNKS 782      // ceil(NE / 2048), 8 edges/thread
#define GBLK 782         // ceil(NN / 128) row-blocks for the GEMMs
#define MAXDEG 64        // Poisson(16): P(deg>64) ~ 1e-20

typedef _Float16 f16;
typedef __attribute__((ext_vector_type(2))) _Float16 f16x2;
typedef __attribute__((ext_vector_type(4))) _Float16 f16x4;
typedef __attribute__((ext_vector_type(8))) _Float16 f16x8;
typedef __attribute__((ext_vector_type(4))) float f32x4;

// ---------------- threefry2x32 (JAX-compatible) ----------------
__device__ __forceinline__ uint32_t rotl32(uint32_t x, int r) {
  return __builtin_amdgcn_alignbit(x, x, (32 - r) & 31);
}

__device__ __forceinline__ void tf2x32(uint32_t k0, uint32_t k1,
                                       uint32_t x0, uint32_t x1,
                                       uint32_t &o0, uint32_t &o1) {
  uint32_t ks2 = k0 ^ k1 ^ 0x1BD11BDAu;
#define TF_R(r) { x0 += x1; x1 = rotl32(x1, r); x1 ^= x0; }
  x0 += k0; x1 += k1;
  TF_R(13) TF_R(15) TF_R(26) TF_R(6)
  x0 += k1;  x1 += ks2 + 1u;
  TF_R(17) TF_R(29) TF_R(16) TF_R(24)
  x0 += ks2; x1 += k0 + 2u;
  TF_R(13) TF_R(15) TF_R(26) TF_R(6)
  x0 += k0;  x1 += k1 + 3u;
  TF_R(17) TF_R(29) TF_R(16) TF_R(24)
  x0 += k1;  x1 += ks2 + 4u;
  TF_R(13) TF_R(15) TF_R(26) TF_R(6)
  x0 += ks2; x1 += k0 + 5u;
#undef TF_R
  o0 = x0; o1 = x1;
}

static void tf2x32_host(uint32_t k0, uint32_t k1, uint32_t x0, uint32_t x1,
                        uint32_t *o0, uint32_t *o1) {
  uint32_t ks2 = k0 ^ k1 ^ 0x1BD11BDAu;
#define TF_R(r) { x0 += x1; x1 = (x1 << (r)) | (x1 >> (32 - (r))); x1 ^= x0; }
  x0 += k0; x1 += k1;
  TF_R(13) TF_R(15) TF_R(26) TF_R(6)
  x0 += k1;  x1 += ks2 + 1u;
  TF_R(17) TF_R(29) TF_R(16) TF_R(24)
  x0 += ks2; x1 += k0 + 2u;
  TF_R(13) TF_R(15) TF_R(26) TF_R(6)
  x0 += k0;  x1 += k1 + 3u;
  TF_R(17) TF_R(29) TF_R(16) TF_R(24)
  x0 += k1;  x1 += ks2 + 4u;
  TF_R(13) TF_R(15) TF_R(26) TF_R(6)
  x0 += ks2; x1 += k0 + 5u;
#undef TF_R
  *o0 = x0; *o1 = x1;
}

// ---------------- fill: fixed-stride slots, PLANE-MAJOR, XCD-binned -------
// col2[p*NN + d]: plane p's per-XCD write region is 50 KB and densely
// written for p < ~24 -> lines accumulate ~16 writes in L2 before one
// writeback (R8's node-major layout forced ~1 writeback per write, 78 MB).
// Block bid&7 handles dst range [(bid&7)*XRANGE, +XRANGE) (bid%8 -> XCD
// heuristic); cursor doubles as the degree array.
__global__ __launch_bounds__(256) void fill_xcd(const int *__restrict__ src,
                                                const int *__restrict__ dst,
                                                int *__restrict__ cursor,
                                                int *__restrict__ col2) {
  int x = blockIdx.x & 7;
  int chunk = blockIdx.x >> 3;
  int lo = x * XRANGE, hi = lo + XRANGE;
  int base = chunk * 2048 + threadIdx.x;
#pragma unroll
  for (int t = 0; t < 8; ++t) {
    int e = base + t * 256;
    if (e < NE) {
      int d = dst[e];
      if (d >= lo && d < hi) {
        int p = atomicAdd(&cursor[d], 1);
        if (p < MAXDEG) col2[(size_t)p * NN + d] = src[e];
      }
    }
  }
}

// ---------------- conversions ----------------
__global__ __launch_bounds__(256) void cvt_x_kernel(const float *__restrict__ x,
                                                    f16 *__restrict__ xh) {
  uint32_t i = (blockIdx.x * 256 + threadIdx.x) * 4;
  float4 v = *(const float4 *)(x + i);
  f16x4 o;
  o[0] = (f16)v.x; o[1] = (f16)v.y; o[2] = (f16)v.z; o[3] = (f16)v.w;
  *(f16x4 *)(xh + i) = o;
}

// weights -> fp16, k-major: Wk[col][k] = W[k][col]
__global__ __launch_bounds__(256) void cvt_w_kernel(
    const float *__restrict__ w0, const float *__restrict__ w1,
    const float *__restrict__ w2, const float *__restrict__ lw,
    f16 *__restrict__ Wk0, f16 *__restrict__ Wk1, f16 *__restrict__ Wk2,
    f16 *__restrict__ WkL) {
  int t = blockIdx.x * 256 + threadIdx.x;
  if (t < 3 * 32768) {
    int wi = t >> 15, r = t & 32767;  // r = k*128 + c
    int k = r >> 7, c = r & 127;
    const float *w = (wi == 0) ? w0 : ((wi == 1) ? w1 : w2);
    f16 *o = (wi == 0) ? Wk0 : ((wi == 1) ? Wk1 : Wk2);
    o[c * 256 + k] = (f16)w[r];
  } else {
    int r = t - 3 * 32768;  // r = k*64 + c, r < 8192
    int k = r >> 6, c = r & 63;
    WkL[c * 128 + k] = (f16)lw[r];
  }
}

// ---------------- mean aggregation + fused dropout-mask gen ----------------
// One wave per node; col at col2[p*NN + n] (plane-major): the block's 4
// consecutive nodes share one 64B line per plane -> high L1/L2 reuse.
__global__ __launch_bounds__(256) void agg_kernel(const f16 *__restrict__ h,
                                                  const int *__restrict__ deg,
                                                  const int *__restrict__ col2,
                                                  f16 *__restrict__ agg,
                                                  uint32_t *__restrict__ mrow,
                                                  uint32_t mk0, uint32_t mk1) {
  int wid = threadIdx.x >> 6;
  int lane = threadIdx.x & 63;
  int n = blockIdx.x * 4 + wid;
  if (n >= NN) return;

  // ---- fused mask (independent VALU work; hides under gather latency)
  {
    uint32_t j0 = (uint32_t)n * 128u + (uint32_t)lane;
    uint32_t o0, o1, p0, p1;
    tf2x32(mk0, mk1, 0u, j0, o0, o1);
    tf2x32(mk0, mk1, 0u, j0 + 64u, p0, p1);
    unsigned long long blo = __ballot((int)(o0 ^ o1) >= 0);
    unsigned long long bhi = __ballot((int)(p0 ^ p1) >= 0);
    if (lane == 0) {
      uint4 mv;
      mv.x = (uint32_t)blo; mv.y = (uint32_t)(blo >> 32);
      mv.z = (uint32_t)bhi; mv.w = (uint32_t)(bhi >> 32);
      *(uint4 *)(mrow + (size_t)n * 4) = mv;
    }
  }

  int d = min(deg[n], MAXDEG);
  const int half = lane >> 5;
  const int q = lane & 31;
  float s0 = 0.f, s1 = 0.f, s2 = 0.f, s3 = 0.f;
  int i = 0;
  for (; i + 8 <= d; i += 8) {
    int c0 = col2[(size_t)(i + 0 + half) * NN + n];
    int c1 = col2[(size_t)(i + 2 + half) * NN + n];
    int c2 = col2[(size_t)(i + 4 + half) * NN + n];
    int c3 = col2[(size_t)(i + 6 + half) * NN + n];
    f16x4 v0 = ((const f16x4 *)(h + (size_t)c0 * 128))[q];
    f16x4 v1 = ((const f16x4 *)(h + (size_t)c1 * 128))[q];
    f16x4 v2 = ((const f16x4 *)(h + (size_t)c2 * 128))[q];
    f16x4 v3 = ((const f16x4 *)(h + (size_t)c3 * 128))[q];
    s0 += (float)v0[0] + (float)v1[0] + (float)v2[0] + (float)v3[0];
    s1 += (float)v0[1] + (float)v1[1] + (float)v2[1] + (float)v3[1];
    s2 += (float)v0[2] + (float)v1[2] + (float)v2[2] + (float)v3[2];
    s3 += (float)v0[3] + (float)v1[3] + (float)v2[3] + (float)v3[3];
  }
  for (; i + 2 <= d; i += 2) {
    int c = col2[(size_t)(i + half) * NN + n];
    f16x4 v = ((const f16x4 *)(h + (size_t)c * 128))[q];
    s0 += (float)v[0]; s1 += (float)v[1];
    s2 += (float)v[2]; s3 += (float)v[3];
  }
  if (i < d && half == 0) {
    int c = col2[(size_t)i * NN + n];
    f16x4 v = ((const f16x4 *)(h + (size_t)c * 128))[q];
    s0 += (float)v[0]; s1 += (float)v[1];
    s2 += (float)v[2]; s3 += (float)v[3];
  }
  s0 += __shfl_xor(s0, 32);
  s1 += __shfl_xor(s1, 32);
  s2 += __shfl_xor(s2, 32);
  s3 += __shfl_xor(s3, 32);
  if (half == 0) {
    float inv = 1.0f / (float)max(d, 1);
    f16x4 o;
    o[0] = (f16)(s0 * inv); o[1] = (f16)(s1 * inv);
    o[2] = (f16)(s2 * inv); o[3] = (f16)(s3 * inv);
    ((f16x4 *)(agg + (size_t)n * 128))[q] = o;
  }
}

// ---------------- fused [agg,h]@W + b -> relu -> dropout (MFMA f16) --------
// B-stationary: wave wv owns output cols [wv*32, wv*32+32) as two 16-col
// tiles; its B fragments for all K=256 live in 64 VGPRs (loaded once).
__global__ __launch_bounds__(256) void sage_gemm_f16(
    const f16 *__restrict__ agg, const f16 *__restrict__ hin,
    const f16 *__restrict__ Wk, const float *__restrict__ bias,
    const uint32_t *__restrict__ mask, f16 *__restrict__ hout) {
  const int tid = threadIdx.x;
  const int lane = tid & 63;
  const int wv = tid >> 6;
  const int blk_row0 = blockIdx.x * 128;
  const int kg = (lane >> 4) * 8;
  const int col_lo = lane & 15;

  f16x8 Bf[2][8];
#pragma unroll
  for (int t = 0; t < 2; ++t) {
    const int colb = wv * 32 + t * 16 + col_lo;
#pragma unroll
    for (int ks = 0; ks < 8; ++ks)
      Bf[t][ks] = *(const f16x8 *)(Wk + (size_t)colb * 256 + ks * 32 + kg);
  }
  const float bv0 = bias[wv * 32 + col_lo];
  const float bv1 = bias[wv * 32 + 16 + col_lo];

#pragma unroll 2
  for (int s = 0; s < 8; ++s) {
    const int row0 = blk_row0 + s * 16;
    const int ar = row0 + col_lo;
    const bool rowok = ar < NN;
    f16x8 Af[8];
#pragma unroll
    for (int ks = 0; ks < 8; ++ks) {
      const f16 *asrc = (ks < 4)
                            ? (agg + (size_t)ar * 128 + ks * 32 + kg)
                            : (hin + (size_t)ar * 128 + (ks - 4) * 32 + kg);
      Af[ks] = rowok ? *(const f16x8 *)asrc : (f16x8){};
    }
    f32x4 acc0 = {0.f, 0.f, 0.f, 0.f}, acc1 = {0.f, 0.f, 0.f, 0.f};
#pragma unroll
    for (int ks = 0; ks < 8; ++ks) {
      acc0 = __builtin_amdgcn_mfma_f32_16x16x32_f16(Af[ks], Bf[0][ks], acc0, 0, 0, 0);
      acc1 = __builtin_amdgcn_mfma_f32_16x16x32_f16(Af[ks], Bf[1][ks], acc1, 0, 0, 0);
    }
    const int rbase = row0 + (lane >> 4) * 4;
    const int c0 = wv * 32 + col_lo;
    const int c1 = c0 + 16;
#pragma unroll
    for (int r = 0; r < 4; ++r) {
      const int row = rbase + r;
      if (row < NN) {
        uint32_t mw = mask[(size_t)row * 4 + wv];  // both tiles share word wv
        float z0 = acc0[r] + bv0;
        float z1 = acc1[r] + bv1;
        z0 = (z0 > 0.f && ((mw >> col_lo) & 1u)) ? z0 * 2.f : 0.f;
        z1 = (z1 > 0.f && ((mw >> (16 + col_lo)) & 1u)) ? z1 * 2.f : 0.f;
        hout[(size_t)row * 128 + c0] = (f16)z0;
        hout[(size_t)row * 128 + c1] = (f16)z1;
      }
    }
  }
}

// ---------------- final h @ lin_w + lin_b (MFMA f16, f32 out) ----------------
__global__ __launch_bounds__(256) void final_gemm_f16(
    const f16 *__restrict__ hin, const f16 *__restrict__ WkL,
    const float *__restrict__ bias, float *__restrict__ outp) {
  const int tid = threadIdx.x;
  const int lane = tid & 63;
  const int wv = tid >> 6;       // owns cols [wv*16, +16)
  const int blk_row0 = blockIdx.x * 128;
  const int kg = (lane >> 4) * 8;
  const int col_lo = lane & 15;
  const int c = wv * 16 + col_lo;
  f16x8 Bf[4];
#pragma unroll
  for (int ks = 0; ks < 4; ++ks)
    Bf[ks] = *(const f16x8 *)(WkL + (size_t)c * 128 + ks * 32 + kg);
  const float bv = bias[c];
#pragma unroll 2
  for (int s = 0; s < 8; ++s) {
    const int row0 = blk_row0 + s * 16;
    const int ar = row0 + col_lo;
    const bool rowok = ar < NN;
    f32x4 acc = {0.f, 0.f, 0.f, 0.f};
#pragma unroll
    for (int ks = 0; ks < 4; ++ks) {
      f16x8 a = rowok
                    ? *(const f16x8 *)(hin + (size_t)ar * 128 + ks * 32 + kg)
                    : (f16x8){};
      acc = __builtin_amdgcn_mfma_f32_16x16x32_f16(a, Bf[ks], acc, 0, 0, 0);
    }
    const int rbase = row0 + (lane >> 4) * 4;
#pragma unroll
    for (int r = 0; r < 4; ++r) {
      const int row = rbase + r;
      if (row < NN) outp[(size_t)row * 64 + c] = acc[r] + bv;
    }
  }
}

extern "C" void kernel_launch(void *const *d_in, const int *in_sizes, int n_in,
                              void *d_out, int out_size, void *d_ws,
                              size_t ws_size, hipStream_t stream) {
  (void)in_sizes; (void)n_in; (void)out_size; (void)ws_size;
  const float *x = (const float *)d_in[0];
  const int *edge = (const int *)d_in[1];
  const int *src = edge;
  const int *dst = edge + NE;
  const float *w0 = (const float *)d_in[2];
  const float *b0 = (const float *)d_in[3];
  const float *w1 = (const float *)d_in[4];
  const float *b1 = (const float *)d_in[5];
  const float *w2 = (const float *)d_in[6];
  const float *b2 = (const float *)d_in[7];
  const float *lw = (const float *)d_in[8];
  const float *lb = (const float *)d_in[9];
  float *out = (float *)d_out;

  char *ws = (char *)d_ws;
  f16 *xh  = (f16 *)ws; ws += (size_t)NN * 128 * 2;   // also reused as h3
  f16 *h1  = (f16 *)ws; ws += (size_t)NN * 128 * 2;
  f16 *h2  = (f16 *)ws; ws += (size_t)NN * 128 * 2;
  f16 *agg = (f16 *)ws; ws += (size_t)NN * 128 * 2;
  f16 *Wk0 = (f16 *)ws; ws += 256 * 128 * 2;
  f16 *Wk1 = (f16 *)ws; ws += 256 * 128 * 2;
  f16 *Wk2 = (f16 *)ws; ws += 256 * 128 * 2;
  f16 *WkL = (f16 *)ws; ws += 128 * 64 * 2;
  int *cursor = (int *)ws; ws += (size_t)NN * 4;
  int *col2 = (int *)ws;   ws += (size_t)NN * MAXDEG * 4;
  uint32_t *m0 = (uint32_t *)ws; ws += (size_t)(NFLAT / 32) * 4;
  uint32_t *m1 = (uint32_t *)ws; ws += (size_t)(NFLAT / 32) * 4;
  uint32_t *m2 = (uint32_t *)ws; ws += (size_t)(NFLAT / 32) * 4;

  uint32_t fk[3][2];
  for (int i = 0; i < 3; ++i)
    tf2x32_host(0u, 42u, 0u, (uint32_t)i, &fk[i][0], &fk[i][1]);

  hipMemsetAsync(cursor, 0, (size_t)NN * 4, stream);
  fill_xcd<<<8 * XCHUNKS, 256, 0, stream>>>(src, dst, cursor, col2);
  cvt_x_kernel<<<NFLAT / 1024, 256, 0, stream>>>(x, xh);
  cvt_w_kernel<<<416, 256, 0, stream>>>(w0, w1, w2, lw, Wk0, Wk1, Wk2, WkL);

  // layer 0 (agg also generates m0)
  agg_kernel<<<NN / 4, 256, 0, stream>>>(xh, cursor, col2, agg, m0,
                                         fk[0][0], fk[0][1]);
  sage_gemm_f16<<<GBLK, 256, 0, stream>>>(agg, xh, Wk0, b0, m0, h1);
  // layer 1 (agg also generates m1)
  agg_kernel<<<NN / 4, 256, 0, stream>>>(h1, cursor, col2, agg, m1,
                                         fk[1][0], fk[1][1]);
  sage_gemm_f16<<<GBLK, 256, 0, stream>>>(agg, h1, Wk1, b1, m1, h2);
  // layer 2 (agg also generates m2; output reuses xh buffer)
  agg_kernel<<<NN / 4, 256, 0, stream>>>(h2, cursor, col2, agg, m2,
                                         fk[2][0], fk[2][1]);
  sage_gemm_f16<<<GBLK, 256, 0, stream>>>(agg, h2, Wk2, b2, m2, xh);
  // final linear
  final_gemm_f16<<<GBLK, 256, 0, stream>>>(xh, WkL, lb, out);
}

// Round 13
// 445.308 us; speedup vs baseline: 1.2918x; 1.0612x over previous
//
#include <hip/hip_runtime.h>
#include <stdint.h>

#define NN 100000
#define NE 1600000
#define NFLAT 12800000u  // NN*128
#define XRANGE 12500     // NN / 8 nodes per XCD range
#define XCHUNKS 782      // ceil(NE / 2048), 8 edges/thread
#define GBLK 782         // ceil(NN / 128) row-blocks for the GEMMs
#define MAXDEG 64        // Poisson(16): P(deg>64) ~ 1e-20

typedef _Float16 f16;
typedef __attribute__((ext_vector_type(2))) _Float16 f16x2;
typedef __attribute__((ext_vector_type(4))) _Float16 f16x4;
typedef __attribute__((ext_vector_type(8))) _Float16 f16x8;
typedef __attribute__((ext_vector_type(4))) float f32x4;

// ---------------- threefry2x32 (JAX-compatible) ----------------
__device__ __forceinline__ uint32_t rotl32(uint32_t x, int r) {
  return __builtin_amdgcn_alignbit(x, x, (32 - r) & 31);
}

__device__ __forceinline__ void tf2x32(uint32_t k0, uint32_t k1,
                                       uint32_t x0, uint32_t x1,
                                       uint32_t &o0, uint32_t &o1) {
  uint32_t ks2 = k0 ^ k1 ^ 0x1BD11BDAu;
#define TF_R(r) { x0 += x1; x1 = rotl32(x1, r); x1 ^= x0; }
  x0 += k0; x1 += k1;
  TF_R(13) TF_R(15) TF_R(26) TF_R(6)
  x0 += k1;  x1 += ks2 + 1u;
  TF_R(17) TF_R(29) TF_R(16) TF_R(24)
  x0 += ks2; x1 += k0 + 2u;
  TF_R(13) TF_R(15) TF_R(26) TF_R(6)
  x0 += k0;  x1 += k1 + 3u;
  TF_R(17) TF_R(29) TF_R(16) TF_R(24)
  x0 += k1;  x1 += ks2 + 4u;
  TF_R(13) TF_R(15) TF_R(26) TF_R(6)
  x0 += ks2; x1 += k0 + 5u;
#undef TF_R
  o0 = x0; o1 = x1;
}

static void tf2x32_host(uint32_t k0, uint32_t k1, uint32_t x0, uint32_t x1,
                        uint32_t *o0, uint32_t *o1) {
  uint32_t ks2 = k0 ^ k1 ^ 0x1BD11BDAu;
#define TF_R(r) { x0 += x1; x1 = (x1 << (r)) | (x1 >> (32 - (r))); x1 ^= x0; }
  x0 += k0; x1 += k1;
  TF_R(13) TF_R(15) TF_R(26) TF_R(6)
  x0 += k1;  x1 += ks2 + 1u;
  TF_R(17) TF_R(29) TF_R(16) TF_R(24)
  x0 += ks2; x1 += k0 + 2u;
  TF_R(13) TF_R(15) TF_R(26) TF_R(6)
  x0 += k0;  x1 += k1 + 3u;
  TF_R(17) TF_R(29) TF_R(16) TF_R(24)
  x0 += k1;  x1 += ks2 + 4u;
  TF_R(13) TF_R(15) TF_R(26) TF_R(6)
  x0 += ks2; x1 += k0 + 5u;
#undef TF_R
  *o0 = x0; *o1 = x1;
}

// ---------------- fill: fixed-stride slots, node-major, XCD-binned --------
// col2[d*MAXDEG + p], p = atomicAdd(cursor[d]); cursor doubles as degree.
// ~75 us, BW-saturated on read re-pass + write-allocate thrash; four
// structural alternatives (R9-R11) all measured slower. Accepted.
__global__ __launch_bounds__(256) void fill_xcd(const int *__restrict__ src,
                                                const int *__restrict__ dst,
                                                int *__restrict__ cursor,
                                                int *__restrict__ col2) {
  int x = blockIdx.x & 7;
  int chunk = blockIdx.x >> 3;
  int lo = x * XRANGE, hi = lo + XRANGE;
  int base = chunk * 2048 + threadIdx.x;
#pragma unroll
  for (int t = 0; t < 8; ++t) {
    int e = base + t * 256;
    if (e < NE) {
      int d = dst[e];
      if (d >= lo && d < hi) {
        int p = atomicAdd(&cursor[d], 1);
        if (p < MAXDEG) col2[d * MAXDEG + p] = src[e];
      }
    }
  }
}

// ---------------- conversions ----------------
__global__ __launch_bounds__(256) void cvt_x_kernel(const float *__restrict__ x,
                                                    f16 *__restrict__ xh) {
  uint32_t i = (blockIdx.x * 256 + threadIdx.x) * 4;
  float4 v = *(const float4 *)(x + i);
  f16x4 o;
  o[0] = (f16)v.x; o[1] = (f16)v.y; o[2] = (f16)v.z; o[3] = (f16)v.w;
  *(f16x4 *)(xh + i) = o;
}

// weights -> fp16, k-major: Wk[col][k] = W[k][col]
__global__ __launch_bounds__(256) void cvt_w_kernel(
    const float *__restrict__ w0, const float *__restrict__ w1,
    const float *__restrict__ w2, const float *__restrict__ lw,
    f16 *__restrict__ Wk0, f16 *__restrict__ Wk1, f16 *__restrict__ Wk2,
    f16 *__restrict__ WkL) {
  int t = blockIdx.x * 256 + threadIdx.x;
  if (t < 3 * 32768) {
    int wi = t >> 15, r = t & 32767;  // r = k*128 + c
    int k = r >> 7, c = r & 127;
    const float *w = (wi == 0) ? w0 : ((wi == 1) ? w1 : w2);
    f16 *o = (wi == 0) ? Wk0 : ((wi == 1) ? Wk1 : Wk2);
    o[c * 256 + k] = (f16)w[r];
  } else {
    int r = t - 3 * 32768;  // r = k*64 + c, r < 8192
    int k = r >> 6, c = r & 63;
    WkL[c * 128 + k] = (f16)lw[r];
  }
}

// ---------------- mean aggregation + fused dropout-mask gen ----------------
// One wave per node, 4-edge x 16B-lane gather: lane = q4*16 + r where
// q4 = edge-in-quad, r = channel sixteenth. ONE f16x8 load instruction
// covers 4 edge rows (1 KB in flight vs 512B before); 8-edge loop = 2
// instructions (was 4). Reduce: shfl_xor 16 + 32. Block mapping is
// XCD-aligned (bid&7 selects the node range fill wrote on that XCD) so
// col2 slot reads hit the local L2.
__global__ __launch_bounds__(256) void agg_kernel(const f16 *__restrict__ h,
                                                  const int *__restrict__ deg,
                                                  const int *__restrict__ col2,
                                                  f16 *__restrict__ agg,
                                                  uint32_t *__restrict__ mrow,
                                                  uint32_t mk0, uint32_t mk1) {
  int wid = threadIdx.x >> 6;
  int lane = threadIdx.x & 63;
  int n = (blockIdx.x & 7) * XRANGE + (blockIdx.x >> 3) * 4 + wid;

  // ---- fused mask (independent VALU work; hides under gather latency)
  {
    uint32_t j0 = (uint32_t)n * 128u + (uint32_t)lane;
    uint32_t o0, o1, p0, p1;
    tf2x32(mk0, mk1, 0u, j0, o0, o1);
    tf2x32(mk0, mk1, 0u, j0 + 64u, p0, p1);
    unsigned long long blo = __ballot((int)(o0 ^ o1) >= 0);
    unsigned long long bhi = __ballot((int)(p0 ^ p1) >= 0);
    if (lane == 0) {
      uint4 mv;
      mv.x = (uint32_t)blo; mv.y = (uint32_t)(blo >> 32);
      mv.z = (uint32_t)bhi; mv.w = (uint32_t)(bhi >> 32);
      *(uint4 *)(mrow + (size_t)n * 4) = mv;
    }
  }

  const int beg = n * MAXDEG;
  int d = min(deg[n], MAXDEG);
  const int q4 = lane >> 4;
  const int r = lane & 15;
  float s0 = 0.f, s1 = 0.f, s2 = 0.f, s3 = 0.f;
  float s4 = 0.f, s5 = 0.f, s6 = 0.f, s7 = 0.f;
  int i = 0;
  for (; i + 8 <= d; i += 8) {
    int c0 = col2[beg + i + q4];
    int c1 = col2[beg + i + 4 + q4];
    f16x8 v0 = ((const f16x8 *)(h + (size_t)c0 * 128))[r];
    f16x8 v1 = ((const f16x8 *)(h + (size_t)c1 * 128))[r];
    s0 += (float)v0[0] + (float)v1[0];
    s1 += (float)v0[1] + (float)v1[1];
    s2 += (float)v0[2] + (float)v1[2];
    s3 += (float)v0[3] + (float)v1[3];
    s4 += (float)v0[4] + (float)v1[4];
    s5 += (float)v0[5] + (float)v1[5];
    s6 += (float)v0[6] + (float)v1[6];
    s7 += (float)v0[7] + (float)v1[7];
  }
  for (; i + 4 <= d; i += 4) {
    int c = col2[beg + i + q4];
    f16x8 v = ((const f16x8 *)(h + (size_t)c * 128))[r];
    s0 += (float)v[0]; s1 += (float)v[1];
    s2 += (float)v[2]; s3 += (float)v[3];
    s4 += (float)v[4]; s5 += (float)v[5];
    s6 += (float)v[6]; s7 += (float)v[7];
  }
  if (i < d && q4 < d - i) {
    int c = col2[beg + i + q4];
    f16x8 v = ((const f16x8 *)(h + (size_t)c * 128))[r];
    s0 += (float)v[0]; s1 += (float)v[1];
    s2 += (float)v[2]; s3 += (float)v[3];
    s4 += (float)v[4]; s5 += (float)v[5];
    s6 += (float)v[6]; s7 += (float)v[7];
  }
  s0 += __shfl_xor(s0, 16); s0 += __shfl_xor(s0, 32);
  s1 += __shfl_xor(s1, 16); s1 += __shfl_xor(s1, 32);
  s2 += __shfl_xor(s2, 16); s2 += __shfl_xor(s2, 32);
  s3 += __shfl_xor(s3, 16); s3 += __shfl_xor(s3, 32);
  s4 += __shfl_xor(s4, 16); s4 += __shfl_xor(s4, 32);
  s5 += __shfl_xor(s5, 16); s5 += __shfl_xor(s5, 32);
  s6 += __shfl_xor(s6, 16); s6 += __shfl_xor(s6, 32);
  s7 += __shfl_xor(s7, 16); s7 += __shfl_xor(s7, 32);
  if (q4 == 0) {
    float inv = 1.0f / (float)max(d, 1);
    f16x8 o;
    o[0] = (f16)(s0 * inv); o[1] = (f16)(s1 * inv);
    o[2] = (f16)(s2 * inv); o[3] = (f16)(s3 * inv);
    o[4] = (f16)(s4 * inv); o[5] = (f16)(s5 * inv);
    o[6] = (f16)(s6 * inv); o[7] = (f16)(s7 * inv);
    ((f16x8 *)(agg + (size_t)n * 128))[r] = o;
  }
}

// ---------------- fused [agg,h]@W + b -> relu -> dropout (MFMA f16) --------
// B-stationary: wave wv owns output cols [wv*32, wv*32+32) as two 16-col
// tiles; its B fragments for all K=256 live in 64 VGPRs (loaded once).
__global__ __launch_bounds__(256) void sage_gemm_f16(
    const f16 *__restrict__ agg, const f16 *__restrict__ hin,
    const f16 *__restrict__ Wk, const float *__restrict__ bias,
    const uint32_t *__restrict__ mask, f16 *__restrict__ hout) {
  const int tid = threadIdx.x;
  const int lane = tid & 63;
  const int wv = tid >> 6;
  const int blk_row0 = blockIdx.x * 128;
  const int kg = (lane >> 4) * 8;
  const int col_lo = lane & 15;

  f16x8 Bf[2][8];
#pragma unroll
  for (int t = 0; t < 2; ++t) {
    const int colb = wv * 32 + t * 16 + col_lo;
#pragma unroll
    for (int ks = 0; ks < 8; ++ks)
      Bf[t][ks] = *(const f16x8 *)(Wk + (size_t)colb * 256 + ks * 32 + kg);
  }
  const float bv0 = bias[wv * 32 + col_lo];
  const float bv1 = bias[wv * 32 + 16 + col_lo];

#pragma unroll 2
  for (int s = 0; s < 8; ++s) {
    const int row0 = blk_row0 + s * 16;
    const int ar = row0 + col_lo;
    const bool rowok = ar < NN;
    f16x8 Af[8];
#pragma unroll
    for (int ks = 0; ks < 8; ++ks) {
      const f16 *asrc = (ks < 4)
                            ? (agg + (size_t)ar * 128 + ks * 32 + kg)
                            : (hin + (size_t)ar * 128 + (ks - 4) * 32 + kg);
      Af[ks] = rowok ? *(const f16x8 *)asrc : (f16x8){};
    }
    f32x4 acc0 = {0.f, 0.f, 0.f, 0.f}, acc1 = {0.f, 0.f, 0.f, 0.f};
#pragma unroll
    for (int ks = 0; ks < 8; ++ks) {
      acc0 = __builtin_amdgcn_mfma_f32_16x16x32_f16(Af[ks], Bf[0][ks], acc0, 0, 0, 0);
      acc1 = __builtin_amdgcn_mfma_f32_16x16x32_f16(Af[ks], Bf[1][ks], acc1, 0, 0, 0);
    }
    const int rbase = row0 + (lane >> 4) * 4;
    const int c0 = wv * 32 + col_lo;
    const int c1 = c0 + 16;
#pragma unroll
    for (int r = 0; r < 4; ++r) {
      const int row = rbase + r;
      if (row < NN) {
        uint32_t mw = mask[(size_t)row * 4 + wv];  // both tiles share word wv
        float z0 = acc0[r] + bv0;
        float z1 = acc1[r] + bv1;
        z0 = (z0 > 0.f && ((mw >> col_lo) & 1u)) ? z0 * 2.f : 0.f;
        z1 = (z1 > 0.f && ((mw >> (16 + col_lo)) & 1u)) ? z1 * 2.f : 0.f;
        hout[(size_t)row * 128 + c0] = (f16)z0;
        hout[(size_t)row * 128 + c1] = (f16)z1;
      }
    }
  }
}

// ---------------- final h @ lin_w + lin_b (MFMA f16, f32 out) ----------------
__global__ __launch_bounds__(256) void final_gemm_f16(
    const f16 *__restrict__ hin, const f16 *__restrict__ WkL,
    const float *__restrict__ bias, float *__restrict__ outp) {
  const int tid = threadIdx.x;
  const int lane = tid & 63;
  const int wv = tid >> 6;       // owns cols [wv*16, +16)
  const int blk_row0 = blockIdx.x * 128;
  const int kg = (lane >> 4) * 8;
  const int col_lo = lane & 15;
  const int c = wv * 16 + col_lo;
  f16x8 Bf[4];
#pragma unroll
  for (int ks = 0; ks < 4; ++ks)
    Bf[ks] = *(const f16x8 *)(WkL + (size_t)c * 128 + ks * 32 + kg);
  const float bv = bias[c];
#pragma unroll 2
  for (int s = 0; s < 8; ++s) {
    const int row0 = blk_row0 + s * 16;
    const int ar = row0 + col_lo;
    const bool rowok = ar < NN;
    f32x4 acc = {0.f, 0.f, 0.f, 0.f};
#pragma unroll
    for (int ks = 0; ks < 4; ++ks) {
      f16x8 a = rowok
                    ? *(const f16x8 *)(hin + (size_t)ar * 128 + ks * 32 + kg)
                    : (f16x8){};
      acc = __builtin_amdgcn_mfma_f32_16x16x32_f16(a, Bf[ks], acc, 0, 0, 0);
    }
    const int rbase = row0 + (lane >> 4) * 4;
#pragma unroll
    for (int r = 0; r < 4; ++r) {
      const int row = rbase + r;
      if (row < NN) outp[(size_t)row * 64 + c] = acc[r] + bv;
    }
  }
}

extern "C" void kernel_launch(void *const *d_in, const int *in_sizes, int n_in,
                              void *d_out, int out_size, void *d_ws,
                              size_t ws_size, hipStream_t stream) {
  (void)in_sizes; (void)n_in; (void)out_size; (void)ws_size;
  const float *x = (const float *)d_in[0];
  const int *edge = (const int *)d_in[1];
  const int *src = edge;
  const int *dst = edge + NE;
  const float *w0 = (const float *)d_in[2];
  const float *b0 = (const float *)d_in[3];
  const float *w1 = (const float *)d_in[4];
  const float *b1 = (const float *)d_in[5];
  const float *w2 = (const float *)d_in[6];
  const float *b2 = (const float *)d_in[7];
  const float *lw = (const float *)d_in[8];
  const float *lb = (const float *)d_in[9];
  float *out = (float *)d_out;

  char *ws = (char *)d_ws;
  f16 *xh  = (f16 *)ws; ws += (size_t)NN * 128 * 2;   // also reused as h3
  f16 *h1  = (f16 *)ws; ws += (size_t)NN * 128 * 2;
  f16 *h2  = (f16 *)ws; ws += (size_t)NN * 128 * 2;
  f16 *agg = (f16 *)ws; ws += (size_t)NN * 128 * 2;
  f16 *Wk0 = (f16 *)ws; ws += 256 * 128 * 2;
  f16 *Wk1 = (f16 *)ws; ws += 256 * 128 * 2;
  f16 *Wk2 = (f16 *)ws; ws += 256 * 128 * 2;
  f16 *WkL = (f16 *)ws; ws += 128 * 64 * 2;
  int *cursor = (int *)ws; ws += (size_t)NN * 4;
  int *col2 = (int *)ws;   ws += (size_t)NN * MAXDEG * 4;
  uint32_t *m0 = (uint32_t *)ws; ws += (size_t)(NFLAT / 32) * 4;
  uint32_t *m1 = (uint32_t *)ws; ws += (size_t)(NFLAT / 32) * 4;
  uint32_t *m2 = (uint32_t *)ws; ws += (size_t)(NFLAT / 32) * 4;

  uint32_t fk[3][2];
  for (int i = 0; i < 3; ++i)
    tf2x32_host(0u, 42u, 0u, (uint32_t)i, &fk[i][0], &fk[i][1]);

  hipMemsetAsync(cursor, 0, (size_t)NN * 4, stream);
  fill_xcd<<<8 * XCHUNKS, 256, 0, stream>>>(src, dst, cursor, col2);
  cvt_x_kernel<<<NFLAT / 1024, 256, 0, stream>>>(x, xh);
  cvt_w_kernel<<<416, 256, 0, stream>>>(w0, w1, w2, lw, Wk0, Wk1, Wk2, WkL);

  // layer 0 (agg also generates m0)
  agg_kernel<<<NN / 4, 256, 0, stream>>>(xh, cursor, col2, agg, m0,
                                         fk[0][0], fk[0][1]);
  sage_gemm_f16<<<GBLK, 256, 0, stream>>>(agg, xh, Wk0, b0, m0, h1);
  // layer 1 (agg also generates m1)
  agg_kernel<<<NN / 4, 256, 0, stream>>>(h1, cursor, col2, agg, m1,
                                         fk[1][0], fk[1][1]);
  sage_gemm_f16<<<GBLK, 256, 0, stream>>>(agg, h1, Wk1, b1, m1, h2);
  // layer 2 (agg also generates m2; output reuses xh buffer)
  agg_kernel<<<NN / 4, 256, 0, stream>>>(h2, cursor, col2, agg, m2,
                                         fk[2][0], fk[2][1]);
  sage_gemm_f16<<<GBLK, 256, 0, stream>>>(agg, h2, Wk2, b2, m2, xh);
  // final linear
  final_gemm_f16<<<GBLK, 256, 0, stream>>>(xh, WkL, lb, out);
}

// Round 14
// 442.670 us; speedup vs baseline: 1.2995x; 1.0060x over previous
//
#include <hip/hip_runtime.h>
#include <stdint.h>

#define NN 100000
#define NE 1600000
#define NFLAT 12800000u  // NN*128
#define XRANGE 12500     // NN / 8 nodes per XCD range
#define XCHUNKS 782      // ceil(NE / 2048), 8 edges/thread
#define GBLK 782         // ceil(NN / 128) row-blocks for the GEMMs
#define MAXDEG 64        // Poisson(16): P(deg>64) ~ 1e-20

typedef _Float16 f16;
typedef __attribute__((ext_vector_type(2))) _Float16 f16x2;
typedef __attribute__((ext_vector_type(4))) _Float16 f16x4;
typedef __attribute__((ext_vector_type(8))) _Float16 f16x8;
typedef __attribute__((ext_vector_type(4))) float f32x4;

// ---------------- threefry2x32 (JAX-compatible) ----------------
__device__ __forceinline__ uint32_t rotl32(uint32_t x, int r) {
  return __builtin_amdgcn_alignbit(x, x, (32 - r) & 31);
}

__device__ __forceinline__ void tf2x32(uint32_t k0, uint32_t k1,
                                       uint32_t x0, uint32_t x1,
                                       uint32_t &o0, uint32_t &o1) {
  uint32_t ks2 = k0 ^ k1 ^ 0x1BD11BDAu;
#define TF_R(r) { x0 += x1; x1 = rotl32(x1, r); x1 ^= x0; }
  x0 += k0; x1 += k1;
  TF_R(13) TF_R(15) TF_R(26) TF_R(6)
  x0 += k1;  x1 += ks2 + 1u;
  TF_R(17) TF_R(29) TF_R(16) TF_R(24)
  x0 += ks2; x1 += k0 + 2u;
  TF_R(13) TF_R(15) TF_R(26) TF_R(6)
  x0 += k0;  x1 += k1 + 3u;
  TF_R(17) TF_R(29) TF_R(16) TF_R(24)
  x0 += k1;  x1 += ks2 + 4u;
  TF_R(13) TF_R(15) TF_R(26) TF_R(6)
  x0 += ks2; x1 += k0 + 5u;
#undef TF_R
  o0 = x0; o1 = x1;
}

static void tf2x32_host(uint32_t k0, uint32_t k1, uint32_t x0, uint32_t x1,
                        uint32_t *o0, uint32_t *o1) {
  uint32_t ks2 = k0 ^ k1 ^ 0x1BD11BDAu;
#define TF_R(r) { x0 += x1; x1 = (x1 << (r)) | (x1 >> (32 - (r))); x1 ^= x0; }
  x0 += k0; x1 += k1;
  TF_R(13) TF_R(15) TF_R(26) TF_R(6)
  x0 += k1;  x1 += ks2 + 1u;
  TF_R(17) TF_R(29) TF_R(16) TF_R(24)
  x0 += ks2; x1 += k0 + 2u;
  TF_R(13) TF_R(15) TF_R(26) TF_R(6)
  x0 += k0;  x1 += k1 + 3u;
  TF_R(17) TF_R(29) TF_R(16) TF_R(24)
  x0 += k1;  x1 += ks2 + 4u;
  TF_R(13) TF_R(15) TF_R(26) TF_R(6)
  x0 += ks2; x1 += k0 + 5u;
#undef TF_R
  *o0 = x0; *o1 = x1;
}

// ---------------- fill: fixed-stride slots, node-major, XCD-binned --------
// col2[d*MAXDEG + p], p = atomicAdd(cursor[d]); cursor doubles as degree.
// ~75-85 us, BW-saturated on read re-pass + write-allocate thrash; four
// structural alternatives (R9-R11) all measured slower. Accepted.
__global__ __launch_bounds__(256) void fill_xcd(const int *__restrict__ src,
                                                const int *__restrict__ dst,
                                                int *__restrict__ cursor,
                                                int *__restrict__ col2) {
  int x = blockIdx.x & 7;
  int chunk = blockIdx.x >> 3;
  int lo = x * XRANGE, hi = lo + XRANGE;
  int base = chunk * 2048 + threadIdx.x;
#pragma unroll
  for (int t = 0; t < 8; ++t) {
    int e = base + t * 256;
    if (e < NE) {
      int d = dst[e];
      if (d >= lo && d < hi) {
        int p = atomicAdd(&cursor[d], 1);
        if (p < MAXDEG) col2[d * MAXDEG + p] = src[e];
      }
    }
  }
}

// ---------------- conversions ----------------
__global__ __launch_bounds__(256) void cvt_x_kernel(const float *__restrict__ x,
                                                    f16 *__restrict__ xh) {
  uint32_t i = (blockIdx.x * 256 + threadIdx.x) * 4;
  float4 v = *(const float4 *)(x + i);
  f16x4 o;
  o[0] = (f16)v.x; o[1] = (f16)v.y; o[2] = (f16)v.z; o[3] = (f16)v.w;
  *(f16x4 *)(xh + i) = o;
}

// weights -> fp16, k-major: Wk[col][k] = W[k][col]
__global__ __launch_bounds__(256) void cvt_w_kernel(
    const float *__restrict__ w0, const float *__restrict__ w1,
    const float *__restrict__ w2, const float *__restrict__ lw,
    f16 *__restrict__ Wk0, f16 *__restrict__ Wk1, f16 *__restrict__ Wk2,
    f16 *__restrict__ WkL) {
  int t = blockIdx.x * 256 + threadIdx.x;
  if (t < 3 * 32768) {
    int wi = t >> 15, r = t & 32767;  // r = k*128 + c
    int k = r >> 7, c = r & 127;
    const float *w = (wi == 0) ? w0 : ((wi == 1) ? w1 : w2);
    f16 *o = (wi == 0) ? Wk0 : ((wi == 1) ? Wk1 : Wk2);
    o[c * 256 + k] = (f16)w[r];
  } else {
    int r = t - 3 * 32768;  // r = k*64 + c, r < 8192
    int k = r >> 6, c = r & 63;
    WkL[c * 128 + k] = (f16)lw[r];
  }
}

// ---------------- mean aggregation + fused dropout-mask gen ----------------
// One wave per node, 4-edge x 16B-lane gather (lane = q4*16 + r). Main loop
// unrolled to 16 edges -> FOUR independent f16x8 gathers in flight (R13 had
// two): deg~Poisson(16) means ~half the nodes finish the main loop in one
// iteration of fully-overlapped loads. Reduce: shfl_xor 16 + 32.
__global__ __launch_bounds__(256) void agg_kernel(const f16 *__restrict__ h,
                                                  const int *__restrict__ deg,
                                                  const int *__restrict__ col2,
                                                  f16 *__restrict__ agg,
                                                  uint32_t *__restrict__ mrow,
                                                  uint32_t mk0, uint32_t mk1) {
  int wid = threadIdx.x >> 6;
  int lane = threadIdx.x & 63;
  int n = (blockIdx.x & 7) * XRANGE + (blockIdx.x >> 3) * 4 + wid;

  // ---- fused mask (independent VALU work; hides under gather latency)
  {
    uint32_t j0 = (uint32_t)n * 128u + (uint32_t)lane;
    uint32_t o0, o1, p0, p1;
    tf2x32(mk0, mk1, 0u, j0, o0, o1);
    tf2x32(mk0, mk1, 0u, j0 + 64u, p0, p1);
    unsigned long long blo = __ballot((int)(o0 ^ o1) >= 0);
    unsigned long long bhi = __ballot((int)(p0 ^ p1) >= 0);
    if (lane == 0) {
      uint4 mv;
      mv.x = (uint32_t)blo; mv.y = (uint32_t)(blo >> 32);
      mv.z = (uint32_t)bhi; mv.w = (uint32_t)(bhi >> 32);
      *(uint4 *)(mrow + (size_t)n * 4) = mv;
    }
  }

  const int beg = n * MAXDEG;
  int d = min(deg[n], MAXDEG);
  const int q4 = lane >> 4;
  const int r = lane & 15;
  float s0 = 0.f, s1 = 0.f, s2 = 0.f, s3 = 0.f;
  float s4 = 0.f, s5 = 0.f, s6 = 0.f, s7 = 0.f;
  int i = 0;
  for (; i + 16 <= d; i += 16) {
    int c0 = col2[beg + i + q4];
    int c1 = col2[beg + i + 4 + q4];
    int c2 = col2[beg + i + 8 + q4];
    int c3 = col2[beg + i + 12 + q4];
    f16x8 v0 = ((const f16x8 *)(h + (size_t)c0 * 128))[r];
    f16x8 v1 = ((const f16x8 *)(h + (size_t)c1 * 128))[r];
    f16x8 v2 = ((const f16x8 *)(h + (size_t)c2 * 128))[r];
    f16x8 v3 = ((const f16x8 *)(h + (size_t)c3 * 128))[r];
    s0 += (float)v0[0] + (float)v1[0] + (float)v2[0] + (float)v3[0];
    s1 += (float)v0[1] + (float)v1[1] + (float)v2[1] + (float)v3[1];
    s2 += (float)v0[2] + (float)v1[2] + (float)v2[2] + (float)v3[2];
    s3 += (float)v0[3] + (float)v1[3] + (float)v2[3] + (float)v3[3];
    s4 += (float)v0[4] + (float)v1[4] + (float)v2[4] + (float)v3[4];
    s5 += (float)v0[5] + (float)v1[5] + (float)v2[5] + (float)v3[5];
    s6 += (float)v0[6] + (float)v1[6] + (float)v2[6] + (float)v3[6];
    s7 += (float)v0[7] + (float)v1[7] + (float)v2[7] + (float)v3[7];
  }
  for (; i + 8 <= d; i += 8) {
    int c0 = col2[beg + i + q4];
    int c1 = col2[beg + i + 4 + q4];
    f16x8 v0 = ((const f16x8 *)(h + (size_t)c0 * 128))[r];
    f16x8 v1 = ((const f16x8 *)(h + (size_t)c1 * 128))[r];
    s0 += (float)v0[0] + (float)v1[0];
    s1 += (float)v0[1] + (float)v1[1];
    s2 += (float)v0[2] + (float)v1[2];
    s3 += (float)v0[3] + (float)v1[3];
    s4 += (float)v0[4] + (float)v1[4];
    s5 += (float)v0[5] + (float)v1[5];
    s6 += (float)v0[6] + (float)v1[6];
    s7 += (float)v0[7] + (float)v1[7];
  }
  for (; i + 4 <= d; i += 4) {
    int c = col2[beg + i + q4];
    f16x8 v = ((const f16x8 *)(h + (size_t)c * 128))[r];
    s0 += (float)v[0]; s1 += (float)v[1];
    s2 += (float)v[2]; s3 += (float)v[3];
    s4 += (float)v[4]; s5 += (float)v[5];
    s6 += (float)v[6]; s7 += (float)v[7];
  }
  if (i < d && q4 < d - i) {
    int c = col2[beg + i + q4];
    f16x8 v = ((const f16x8 *)(h + (size_t)c * 128))[r];
    s0 += (float)v[0]; s1 += (float)v[1];
    s2 += (float)v[2]; s3 += (float)v[3];
    s4 += (float)v[4]; s5 += (float)v[5];
    s6 += (float)v[6]; s7 += (float)v[7];
  }
  s0 += __shfl_xor(s0, 16); s0 += __shfl_xor(s0, 32);
  s1 += __shfl_xor(s1, 16); s1 += __shfl_xor(s1, 32);
  s2 += __shfl_xor(s2, 16); s2 += __shfl_xor(s2, 32);
  s3 += __shfl_xor(s3, 16); s3 += __shfl_xor(s3, 32);
  s4 += __shfl_xor(s4, 16); s4 += __shfl_xor(s4, 32);
  s5 += __shfl_xor(s5, 16); s5 += __shfl_xor(s5, 32);
  s6 += __shfl_xor(s6, 16); s6 += __shfl_xor(s6, 32);
  s7 += __shfl_xor(s7, 16); s7 += __shfl_xor(s7, 32);
  if (q4 == 0) {
    float inv = 1.0f / (float)max(d, 1);
    f16x8 o;
    o[0] = (f16)(s0 * inv); o[1] = (f16)(s1 * inv);
    o[2] = (f16)(s2 * inv); o[3] = (f16)(s3 * inv);
    o[4] = (f16)(s4 * inv); o[5] = (f16)(s5 * inv);
    o[6] = (f16)(s6 * inv); o[7] = (f16)(s7 * inv);
    ((f16x8 *)(agg + (size_t)n * 128))[r] = o;
  }
}

// ---------------- fused [agg,h]@W + b -> relu -> dropout (MFMA f16) --------
// B-stationary + explicit A double-buffer: strip s+1's 8 A-loads are issued
// BEFORE strip s's MFMA/epilogue, hiding the ~200cy L2 latency under 16
// MFMAs + stores. Named AfA/AfB buffers (static indexing -> registers).
__global__ __launch_bounds__(256) void sage_gemm_f16(
    const f16 *__restrict__ agg, const f16 *__restrict__ hin,
    const f16 *__restrict__ Wk, const float *__restrict__ bias,
    const uint32_t *__restrict__ mask, f16 *__restrict__ hout) {
  const int tid = threadIdx.x;
  const int lane = tid & 63;
  const int wv = tid >> 6;
  const int blk_row0 = blockIdx.x * 128;
  const int kg = (lane >> 4) * 8;
  const int col_lo = lane & 15;

  f16x8 Bf[2][8];
#pragma unroll
  for (int t = 0; t < 2; ++t) {
    const int colb = wv * 32 + t * 16 + col_lo;
#pragma unroll
    for (int ks = 0; ks < 8; ++ks)
      Bf[t][ks] = *(const f16x8 *)(Wk + (size_t)colb * 256 + ks * 32 + kg);
  }
  const float bv0 = bias[wv * 32 + col_lo];
  const float bv1 = bias[wv * 32 + 16 + col_lo];

  f16x8 AfA[8], AfB[8];

#define LOAD_A(buf, srow)                                                    \
  {                                                                          \
    const int ar_ = (srow) + col_lo;                                         \
    const bool rowok_ = ar_ < NN;                                            \
    _Pragma("unroll") for (int ks = 0; ks < 8; ++ks) {                       \
      const f16 *asrc_ = (ks < 4)                                            \
                             ? (agg + (size_t)ar_ * 128 + ks * 32 + kg)      \
                             : (hin + (size_t)ar_ * 128 + (ks - 4) * 32 + kg); \
      buf[ks] = rowok_ ? *(const f16x8 *)asrc_ : (f16x8){};                  \
    }                                                                        \
  }

#define COMPUTE_STORE(buf, srow)                                             \
  {                                                                          \
    f32x4 acc0 = {0.f, 0.f, 0.f, 0.f}, acc1 = {0.f, 0.f, 0.f, 0.f};          \
    _Pragma("unroll") for (int ks = 0; ks < 8; ++ks) {                       \
      acc0 = __builtin_amdgcn_mfma_f32_16x16x32_f16(buf[ks], Bf[0][ks],      \
                                                    acc0, 0, 0, 0);          \
      acc1 = __builtin_amdgcn_mfma_f32_16x16x32_f16(buf[ks], Bf[1][ks],      \
                                                    acc1, 0, 0, 0);          \
    }                                                                        \
    const int rbase_ = (srow) + (lane >> 4) * 4;                             \
    const int c0_ = wv * 32 + col_lo;                                        \
    _Pragma("unroll") for (int r = 0; r < 4; ++r) {                          \
      const int row_ = rbase_ + r;                                           \
      if (row_ < NN) {                                                       \
        uint32_t mw_ = mask[(size_t)row_ * 4 + wv];                          \
        float z0_ = acc0[r] + bv0;                                           \
        float z1_ = acc1[r] + bv1;                                           \
        z0_ = (z0_ > 0.f && ((mw_ >> col_lo) & 1u)) ? z0_ * 2.f : 0.f;       \
        z1_ = (z1_ > 0.f && ((mw_ >> (16 + col_lo)) & 1u)) ? z1_ * 2.f : 0.f;\
        hout[(size_t)row_ * 128 + c0_] = (f16)z0_;                           \
        hout[(size_t)row_ * 128 + c0_ + 16] = (f16)z1_;                      \
      }                                                                      \
    }                                                                        \
  }

  LOAD_A(AfA, blk_row0);
#pragma unroll
  for (int sp = 0; sp < 8; sp += 2) {
    if (sp + 1 < 8) LOAD_A(AfB, blk_row0 + (sp + 1) * 16);
    COMPUTE_STORE(AfA, blk_row0 + sp * 16);
    if (sp + 2 < 8) LOAD_A(AfA, blk_row0 + (sp + 2) * 16);
    COMPUTE_STORE(AfB, blk_row0 + (sp + 1) * 16);
  }
#undef LOAD_A
#undef COMPUTE_STORE
}

// ---------------- final h @ lin_w + lin_b (MFMA f16, f32 out) ----------------
__global__ __launch_bounds__(256) void final_gemm_f16(
    const f16 *__restrict__ hin, const f16 *__restrict__ WkL,
    const float *__restrict__ bias, float *__restrict__ outp) {
  const int tid = threadIdx.x;
  const int lane = tid & 63;
  const int wv = tid >> 6;       // owns cols [wv*16, +16)
  const int blk_row0 = blockIdx.x * 128;
  const int kg = (lane >> 4) * 8;
  const int col_lo = lane & 15;
  const int c = wv * 16 + col_lo;
  f16x8 Bf[4];
#pragma unroll
  for (int ks = 0; ks < 4; ++ks)
    Bf[ks] = *(const f16x8 *)(WkL + (size_t)c * 128 + ks * 32 + kg);
  const float bv = bias[c];
#pragma unroll 2
  for (int s = 0; s < 8; ++s) {
    const int row0 = blk_row0 + s * 16;
    const int ar = row0 + col_lo;
    const bool rowok = ar < NN;
    f32x4 acc = {0.f, 0.f, 0.f, 0.f};
#pragma unroll
    for (int ks = 0; ks < 4; ++ks) {
      f16x8 a = rowok
                    ? *(const f16x8 *)(hin + (size_t)ar * 128 + ks * 32 + kg)
                    : (f16x8){};
      acc = __builtin_amdgcn_mfma_f32_16x16x32_f16(a, Bf[ks], acc, 0, 0, 0);
    }
    const int rbase = row0 + (lane >> 4) * 4;
#pragma unroll
    for (int r = 0; r < 4; ++r) {
      const int row = rbase + r;
      if (row < NN) outp[(size_t)row * 64 + c] = acc[r] + bv;
    }
  }
}

extern "C" void kernel_launch(void *const *d_in, const int *in_sizes, int n_in,
                              void *d_out, int out_size, void *d_ws,
                              size_t ws_size, hipStream_t stream) {
  (void)in_sizes; (void)n_in; (void)out_size; (void)ws_size;
  const float *x = (const float *)d_in[0];
  const int *edge = (const int *)d_in[1];
  const int *src = edge;
  const int *dst = edge + NE;
  const float *w0 = (const float *)d_in[2];
  const float *b0 = (const float *)d_in[3];
  const float *w1 = (const float *)d_in[4];
  const float *b1 = (const float *)d_in[5];
  const float *w2 = (const float *)d_in[6];
  const float *b2 = (const float *)d_in[7];
  const float *lw = (const float *)d_in[8];
  const float *lb = (const float *)d_in[9];
  float *out = (float *)d_out;

  char *ws = (char *)d_ws;
  f16 *xh  = (f16 *)ws; ws += (size_t)NN * 128 * 2;   // also reused as h3
  f16 *h1  = (f16 *)ws; ws += (size_t)NN * 128 * 2;
  f16 *h2  = (f16 *)ws; ws += (size_t)NN * 128 * 2;
  f16 *agg = (f16 *)ws; ws += (size_t)NN * 128 * 2;
  f16 *Wk0 = (f16 *)ws; ws += 256 * 128 * 2;
  f16 *Wk1 = (f16 *)ws; ws += 256 * 128 * 2;
  f16 *Wk2 = (f16 *)ws; ws += 256 * 128 * 2;
  f16 *WkL = (f16 *)ws; ws += 128 * 64 * 2;
  int *cursor = (int *)ws; ws += (size_t)NN * 4;
  int *col2 = (int *)ws;   ws += (size_t)NN * MAXDEG * 4;
  uint32_t *m0 = (uint32_t *)ws; ws += (size_t)(NFLAT / 32) * 4;
  uint32_t *m1 = (uint32_t *)ws; ws += (size_t)(NFLAT / 32) * 4;
  uint32_t *m2 = (uint32_t *)ws; ws += (size_t)(NFLAT / 32) * 4;

  uint32_t fk[3][2];
  for (int i = 0; i < 3; ++i)
    tf2x32_host(0u, 42u, 0u, (uint32_t)i, &fk[i][0], &fk[i][1]);

  hipMemsetAsync(cursor, 0, (size_t)NN * 4, stream);
  fill_xcd<<<8 * XCHUNKS, 256, 0, stream>>>(src, dst, cursor, col2);
  cvt_x_kernel<<<NFLAT / 1024, 256, 0, stream>>>(x, xh);
  cvt_w_kernel<<<416, 256, 0, stream>>>(w0, w1, w2, lw, Wk0, Wk1, Wk2, WkL);

  // layer 0 (agg also generates m0)
  agg_kernel<<<NN / 4, 256, 0, stream>>>(xh, cursor, col2, agg, m0,
                                         fk[0][0], fk[0][1]);
  sage_gemm_f16<<<GBLK, 256, 0, stream>>>(agg, xh, Wk0, b0, m0, h1);
  // layer 1 (agg also generates m1)
  agg_kernel<<<NN / 4, 256, 0, stream>>>(h1, cursor, col2, agg, m1,
                                         fk[1][0], fk[1][1]);
  sage_gemm_f16<<<GBLK, 256, 0, stream>>>(agg, h1, Wk1, b1, m1, h2);
  // layer 2 (agg also generates m2; output reuses xh buffer)
  agg_kernel<<<NN / 4, 256, 0, stream>>>(h2, cursor, col2, agg, m2,
                                         fk[2][0], fk[2][1]);
  sage_gemm_f16<<<GBLK, 256, 0, stream>>>(agg, h2, Wk2, b2, m2, xh);
  // final linear
  final_gemm_f16<<<GBLK, 256, 0, stream>>>(xh, WkL, lb, out);
}

// Round 15
// 415.822 us; speedup vs baseline: 1.3834x; 1.0646x over previous
//
#include <hip/hip_runtime.h>
#include <stdint.h>

#define NN 100000
#define NE 1600000
#define NFLAT 12800000u  // NN*128
#define XRANGE 12500     // NN / 8 nodes per XCD range
#define XCHUNKS 782      // ceil(NE / 2048), 8 edges/thread
#define GBLK 782         // ceil(NN / 128) row-blocks for the GEMMs
#define MAXDEG 64        // Poisson(16): P(deg>64) ~ 1e-20
#define FILLB (8 * XCHUNKS)   // 6256 fill blocks (multiple of 8 -> XCD map ok)
#define CVTXB 12500           // cvt_x blocks (12.8M elems / (256*4))
#define CVTWB 416             // cvt_w blocks (106496 threads)
#define LDSW 136              // padded LDS row width (f16) for FINAL tile

typedef _Float16 f16;
typedef __attribute__((ext_vector_type(2))) _Float16 f16x2;
typedef __attribute__((ext_vector_type(4))) _Float16 f16x4;
typedef __attribute__((ext_vector_type(8))) _Float16 f16x8;
typedef __attribute__((ext_vector_type(4))) float f32x4;

// ---------------- threefry2x32 (JAX-compatible) ----------------
__device__ __forceinline__ uint32_t rotl32(uint32_t x, int r) {
  return __builtin_amdgcn_alignbit(x, x, (32 - r) & 31);
}

__device__ __forceinline__ void tf2x32(uint32_t k0, uint32_t k1,
                                       uint32_t x0, uint32_t x1,
                                       uint32_t &o0, uint32_t &o1) {
  uint32_t ks2 = k0 ^ k1 ^ 0x1BD11BDAu;
#define TF_R(r) { x0 += x1; x1 = rotl32(x1, r); x1 ^= x0; }
  x0 += k0; x1 += k1;
  TF_R(13) TF_R(15) TF_R(26) TF_R(6)
  x0 += k1;  x1 += ks2 + 1u;
  TF_R(17) TF_R(29) TF_R(16) TF_R(24)
  x0 += ks2; x1 += k0 + 2u;
  TF_R(13) TF_R(15) TF_R(26) TF_R(6)
  x0 += k0;  x1 += k1 + 3u;
  TF_R(17) TF_R(29) TF_R(16) TF_R(24)
  x0 += k1;  x1 += ks2 + 4u;
  TF_R(13) TF_R(15) TF_R(26) TF_R(6)
  x0 += ks2; x1 += k0 + 5u;
#undef TF_R
  o0 = x0; o1 = x1;
}

static void tf2x32_host(uint32_t k0, uint32_t k1, uint32_t x0, uint32_t x1,
                        uint32_t *o0, uint32_t *o1) {
  uint32_t ks2 = k0 ^ k1 ^ 0x1BD11BDAu;
#define TF_R(r) { x0 += x1; x1 = (x1 << (r)) | (x1 >> (32 - (r))); x1 ^= x0; }
  x0 += k0; x1 += k1;
  TF_R(13) TF_R(15) TF_R(26) TF_R(6)
  x0 += k1;  x1 += ks2 + 1u;
  TF_R(17) TF_R(29) TF_R(16) TF_R(24)
  x0 += ks2; x1 += k0 + 2u;
  TF_R(13) TF_R(15) TF_R(26) TF_R(6)
  x0 += k0;  x1 += k1 + 3u;
  TF_R(17) TF_R(29) TF_R(16) TF_R(24)
  x0 += k1;  x1 += ks2 + 4u;
  TF_R(13) TF_R(15) TF_R(26) TF_R(6)
  x0 += ks2; x1 += k0 + 5u;
#undef TF_R
  *o0 = x0; *o1 = x1;
}

// ---------------- prep: fill + cvt_x + cvt_w in ONE kernel ----------------
// Block-role split: [0,FILLB) edge fill (XCD-binned, bid&7 mapping intact
// since FILLB%8==0); [FILLB,+CVTXB) x->f16; last CVTWB blocks weights->f16
// k-major. cvt's ~12us of pure BW hides inside fill's latency-bound 85us
// window (fill only uses 1.5 TB/s).
__global__ __launch_bounds__(256) void prep_kernel(
    const int *__restrict__ src, const int *__restrict__ dst,
    int *__restrict__ cursor, int *__restrict__ col2,
    const float *__restrict__ x, f16 *__restrict__ xh,
    const float *__restrict__ w0, const float *__restrict__ w1,
    const float *__restrict__ w2, const float *__restrict__ lw,
    f16 *__restrict__ Wk0, f16 *__restrict__ Wk1, f16 *__restrict__ Wk2,
    f16 *__restrict__ WkL) {
  const int bid = blockIdx.x;
  const int tid = threadIdx.x;
  if (bid < FILLB) {
    // ---- fill: col2[d*MAXDEG+p], cursor doubles as degree. ~85us,
    // BW-saturated; R9-R11 alternatives all slower. Accepted.
    int xr = bid & 7;
    int chunk = bid >> 3;
    int lo = xr * XRANGE, hi = lo + XRANGE;
    int base = chunk * 2048 + tid;
#pragma unroll
    for (int t = 0; t < 8; ++t) {
      int e = base + t * 256;
      if (e < NE) {
        int d = dst[e];
        if (d >= lo && d < hi) {
          int p = atomicAdd(&cursor[d], 1);
          if (p < MAXDEG) col2[d * MAXDEG + p] = src[e];
        }
      }
    }
  } else if (bid < FILLB + CVTXB) {
    uint32_t i = (uint32_t)(bid - FILLB) * 1024u + (uint32_t)tid * 4u;
    float4 v = *(const float4 *)(x + i);
    f16x4 o;
    o[0] = (f16)v.x; o[1] = (f16)v.y; o[2] = (f16)v.z; o[3] = (f16)v.w;
    *(f16x4 *)(xh + i) = o;
  } else {
    int t = (bid - FILLB - CVTXB) * 256 + tid;
    if (t < 3 * 32768) {
      int wi = t >> 15, r = t & 32767;  // r = k*128 + c
      int k = r >> 7, c = r & 127;
      const float *w = (wi == 0) ? w0 : ((wi == 1) ? w1 : w2);
      f16 *o = (wi == 0) ? Wk0 : ((wi == 1) ? Wk1 : Wk2);
      o[c * 256 + k] = (f16)w[r];
    } else {
      int r = t - 3 * 32768;  // r = k*64 + c, r < 8192
      int k = r >> 6, c = r & 63;
      WkL[c * 128 + k] = (f16)lw[r];
    }
  }
}

// ---------------- mean aggregation + fused dropout-mask gen ----------------
// One wave per node, 4-edge x 16B-lane gather (lane = q4*16 + r), 16-edge
// unroll (4 independent f16x8 gathers in flight). Reduce: shfl_xor 16+32.
__global__ __launch_bounds__(256) void agg_kernel(const f16 *__restrict__ h,
                                                  const int *__restrict__ deg,
                                                  const int *__restrict__ col2,
                                                  f16 *__restrict__ agg,
                                                  uint32_t *__restrict__ mrow,
                                                  uint32_t mk0, uint32_t mk1) {
  int wid = threadIdx.x >> 6;
  int lane = threadIdx.x & 63;
  int n = (blockIdx.x & 7) * XRANGE + (blockIdx.x >> 3) * 4 + wid;

  // ---- fused mask (independent VALU work; hides under gather latency)
  {
    uint32_t j0 = (uint32_t)n * 128u + (uint32_t)lane;
    uint32_t o0, o1, p0, p1;
    tf2x32(mk0, mk1, 0u, j0, o0, o1);
    tf2x32(mk0, mk1, 0u, j0 + 64u, p0, p1);
    unsigned long long blo = __ballot((int)(o0 ^ o1) >= 0);
    unsigned long long bhi = __ballot((int)(p0 ^ p1) >= 0);
    if (lane == 0) {
      uint4 mv;
      mv.x = (uint32_t)blo; mv.y = (uint32_t)(blo >> 32);
      mv.z = (uint32_t)bhi; mv.w = (uint32_t)(bhi >> 32);
      *(uint4 *)(mrow + (size_t)n * 4) = mv;
    }
  }

  const int beg = n * MAXDEG;
  int d = min(deg[n], MAXDEG);
  const int q4 = lane >> 4;
  const int r = lane & 15;
  float s0 = 0.f, s1 = 0.f, s2 = 0.f, s3 = 0.f;
  float s4 = 0.f, s5 = 0.f, s6 = 0.f, s7 = 0.f;
  int i = 0;
  for (; i + 16 <= d; i += 16) {
    int c0 = col2[beg + i + q4];
    int c1 = col2[beg + i + 4 + q4];
    int c2 = col2[beg + i + 8 + q4];
    int c3 = col2[beg + i + 12 + q4];
    f16x8 v0 = ((const f16x8 *)(h + (size_t)c0 * 128))[r];
    f16x8 v1 = ((const f16x8 *)(h + (size_t)c1 * 128))[r];
    f16x8 v2 = ((const f16x8 *)(h + (size_t)c2 * 128))[r];
    f16x8 v3 = ((const f16x8 *)(h + (size_t)c3 * 128))[r];
    s0 += (float)v0[0] + (float)v1[0] + (float)v2[0] + (float)v3[0];
    s1 += (float)v0[1] + (float)v1[1] + (float)v2[1] + (float)v3[1];
    s2 += (float)v0[2] + (float)v1[2] + (float)v2[2] + (float)v3[2];
    s3 += (float)v0[3] + (float)v1[3] + (float)v2[3] + (float)v3[3];
    s4 += (float)v0[4] + (float)v1[4] + (float)v2[4] + (float)v3[4];
    s5 += (float)v0[5] + (float)v1[5] + (float)v2[5] + (float)v3[5];
    s6 += (float)v0[6] + (float)v1[6] + (float)v2[6] + (float)v3[6];
    s7 += (float)v0[7] + (float)v1[7] + (float)v2[7] + (float)v3[7];
  }
  for (; i + 8 <= d; i += 8) {
    int c0 = col2[beg + i + q4];
    int c1 = col2[beg + i + 4 + q4];
    f16x8 v0 = ((const f16x8 *)(h + (size_t)c0 * 128))[r];
    f16x8 v1 = ((const f16x8 *)(h + (size_t)c1 * 128))[r];
    s0 += (float)v0[0] + (float)v1[0];
    s1 += (float)v0[1] + (float)v1[1];
    s2 += (float)v0[2] + (float)v1[2];
    s3 += (float)v0[3] + (float)v1[3];
    s4 += (float)v0[4] + (float)v1[4];
    s5 += (float)v0[5] + (float)v1[5];
    s6 += (float)v0[6] + (float)v1[6];
    s7 += (float)v0[7] + (float)v1[7];
  }
  for (; i + 4 <= d; i += 4) {
    int c = col2[beg + i + q4];
    f16x8 v = ((const f16x8 *)(h + (size_t)c * 128))[r];
    s0 += (float)v[0]; s1 += (float)v[1];
    s2 += (float)v[2]; s3 += (float)v[3];
    s4 += (float)v[4]; s5 += (float)v[5];
    s6 += (float)v[6]; s7 += (float)v[7];
  }
  if (i < d && q4 < d - i) {
    int c = col2[beg + i + q4];
    f16x8 v = ((const f16x8 *)(h + (size_t)c * 128))[r];
    s0 += (float)v[0]; s1 += (float)v[1];
    s2 += (float)v[2]; s3 += (float)v[3];
    s4 += (float)v[4]; s5 += (float)v[5];
    s6 += (float)v[6]; s7 += (float)v[7];
  }
  s0 += __shfl_xor(s0, 16); s0 += __shfl_xor(s0, 32);
  s1 += __shfl_xor(s1, 16); s1 += __shfl_xor(s1, 32);
  s2 += __shfl_xor(s2, 16); s2 += __shfl_xor(s2, 32);
  s3 += __shfl_xor(s3, 16); s3 += __shfl_xor(s3, 32);
  s4 += __shfl_xor(s4, 16); s4 += __shfl_xor(s4, 32);
  s5 += __shfl_xor(s5, 16); s5 += __shfl_xor(s5, 32);
  s6 += __shfl_xor(s6, 16); s6 += __shfl_xor(s6, 32);
  s7 += __shfl_xor(s7, 16); s7 += __shfl_xor(s7, 32);
  if (q4 == 0) {
    float inv = 1.0f / (float)max(d, 1);
    f16x8 o;
    o[0] = (f16)(s0 * inv); o[1] = (f16)(s1 * inv);
    o[2] = (f16)(s2 * inv); o[3] = (f16)(s3 * inv);
    o[4] = (f16)(s4 * inv); o[5] = (f16)(s5 * inv);
    o[6] = (f16)(s6 * inv); o[7] = (f16)(s7 * inv);
    ((f16x8 *)(agg + (size_t)n * 128))[r] = o;
  }
}

// ---------------- fused [agg,h]@W + b -> relu -> dropout (MFMA f16) --------
// B-stationary: wave wv owns output cols [wv*32, +32) as two 16-col tiles;
// B fragments for all K=256 live in 64 VGPRs. FINAL=1 (layer 2): epilogue
// stores h3 to a padded LDS tile instead of global, then each wave computes
// its 16-col strip of out = h3 @ WkL + lb with A from LDS — eliminates the
// 25.6MB h3 write + read and the separate final_gemm dispatch. Rows >= NN
// read garbage LDS but only feed discarded output rows (16x16 MFMA is
// row-isolated). Dynamic LDS: 0 for FINAL=0, 128*LDSW*2 for FINAL=1.
template <int FINAL>
__global__ __launch_bounds__(256) void sage_gemm_f16(
    const f16 *__restrict__ agg, const f16 *__restrict__ hin,
    const f16 *__restrict__ Wk, const float *__restrict__ bias,
    const uint32_t *__restrict__ mask, f16 *__restrict__ hout,
    const f16 *__restrict__ WkL, const float *__restrict__ lb,
    float *__restrict__ outp) {
  extern __shared__ char smem[];
  f16 (*hl)[LDSW] = (f16(*)[LDSW])smem;
  const int tid = threadIdx.x;
  const int lane = tid & 63;
  const int wv = tid >> 6;
  const int blk_row0 = blockIdx.x * 128;
  const int kg = (lane >> 4) * 8;
  const int col_lo = lane & 15;

  f16x8 Bf[2][8];
#pragma unroll
  for (int t = 0; t < 2; ++t) {
    const int colb = wv * 32 + t * 16 + col_lo;
#pragma unroll
    for (int ks = 0; ks < 8; ++ks)
      Bf[t][ks] = *(const f16x8 *)(Wk + (size_t)colb * 256 + ks * 32 + kg);
  }
  const float bv0 = bias[wv * 32 + col_lo];
  const float bv1 = bias[wv * 32 + 16 + col_lo];

#pragma unroll 2
  for (int s = 0; s < 8; ++s) {
    const int row0 = blk_row0 + s * 16;
    const int ar = row0 + col_lo;
    const bool rowok = ar < NN;
    f16x8 Af[8];
#pragma unroll
    for (int ks = 0; ks < 8; ++ks) {
      const f16 *asrc = (ks < 4)
                            ? (agg + (size_t)ar * 128 + ks * 32 + kg)
                            : (hin + (size_t)ar * 128 + (ks - 4) * 32 + kg);
      Af[ks] = rowok ? *(const f16x8 *)asrc : (f16x8){};
    }
    f32x4 acc0 = {0.f, 0.f, 0.f, 0.f}, acc1 = {0.f, 0.f, 0.f, 0.f};
#pragma unroll
    for (int ks = 0; ks < 8; ++ks) {
      acc0 = __builtin_amdgcn_mfma_f32_16x16x32_f16(Af[ks], Bf[0][ks], acc0, 0, 0, 0);
      acc1 = __builtin_amdgcn_mfma_f32_16x16x32_f16(Af[ks], Bf[1][ks], acc1, 0, 0, 0);
    }
    const int rbase = row0 + (lane >> 4) * 4;
    const int c0 = wv * 32 + col_lo;
#pragma unroll
    for (int r = 0; r < 4; ++r) {
      const int row = rbase + r;
      if (row < NN) {
        uint32_t mw = mask[(size_t)row * 4 + wv];  // both tiles share word wv
        float z0 = acc0[r] + bv0;
        float z1 = acc1[r] + bv1;
        z0 = (z0 > 0.f && ((mw >> col_lo) & 1u)) ? z0 * 2.f : 0.f;
        z1 = (z1 > 0.f && ((mw >> (16 + col_lo)) & 1u)) ? z1 * 2.f : 0.f;
        if constexpr (FINAL) {
          const int lr = row - blk_row0;
          hl[lr][c0] = (f16)z0;
          hl[lr][c0 + 16] = (f16)z1;
        } else {
          hout[(size_t)row * 128 + c0] = (f16)z0;
          hout[(size_t)row * 128 + c0 + 16] = (f16)z1;
        }
      }
    }
  }

  if constexpr (FINAL) {
    __syncthreads();
    // wave wv owns out cols [wv*16, +16); A from LDS (pad -> <=2-way banks)
    const int c = wv * 16 + col_lo;
    f16x8 Bf2[4];
#pragma unroll
    for (int ks = 0; ks < 4; ++ks)
      Bf2[ks] = *(const f16x8 *)(WkL + (size_t)c * 128 + ks * 32 + kg);
    const float bv = lb[c];
#pragma unroll 2
    for (int s = 0; s < 8; ++s) {
      const int lr = s * 16 + col_lo;
      f32x4 acc = {0.f, 0.f, 0.f, 0.f};
#pragma unroll
      for (int ks = 0; ks < 4; ++ks) {
        f16x8 a = *(const f16x8 *)&hl[lr][ks * 32 + kg];
        acc = __builtin_amdgcn_mfma_f32_16x16x32_f16(a, Bf2[ks], acc, 0, 0, 0);
      }
      const int rbase = blk_row0 + s * 16 + (lane >> 4) * 4;
#pragma unroll
      for (int r = 0; r < 4; ++r) {
        const int row = rbase + r;
        if (row < NN) outp[(size_t)row * 64 + c] = acc[r] + bv;
      }
    }
  }
}

extern "C" void kernel_launch(void *const *d_in, const int *in_sizes, int n_in,
                              void *d_out, int out_size, void *d_ws,
                              size_t ws_size, hipStream_t stream) {
  (void)in_sizes; (void)n_in; (void)out_size; (void)ws_size;
  const float *x = (const float *)d_in[0];
  const int *edge = (const int *)d_in[1];
  const int *src = edge;
  const int *dst = edge + NE;
  const float *w0 = (const float *)d_in[2];
  const float *b0 = (const float *)d_in[3];
  const float *w1 = (const float *)d_in[4];
  const float *b1 = (const float *)d_in[5];
  const float *w2 = (const float *)d_in[6];
  const float *b2 = (const float *)d_in[7];
  const float *lw = (const float *)d_in[8];
  const float *lb = (const float *)d_in[9];
  float *out = (float *)d_out;

  char *ws = (char *)d_ws;
  f16 *xh  = (f16 *)ws; ws += (size_t)NN * 128 * 2;
  f16 *h1  = (f16 *)ws; ws += (size_t)NN * 128 * 2;
  f16 *h2  = (f16 *)ws; ws += (size_t)NN * 128 * 2;
  f16 *agg = (f16 *)ws; ws += (size_t)NN * 128 * 2;
  f16 *Wk0 = (f16 *)ws; ws += 256 * 128 * 2;
  f16 *Wk1 = (f16 *)ws; ws += 256 * 128 * 2;
  f16 *Wk2 = (f16 *)ws; ws += 256 * 128 * 2;
  f16 *WkL = (f16 *)ws; ws += 128 * 64 * 2;
  int *cursor = (int *)ws; ws += (size_t)NN * 4;
  int *col2 = (int *)ws;   ws += (size_t)NN * MAXDEG * 4;
  uint32_t *m0 = (uint32_t *)ws; ws += (size_t)(NFLAT / 32) * 4;
  uint32_t *m1 = (uint32_t *)ws; ws += (size_t)(NFLAT / 32) * 4;
  uint32_t *m2 = (uint32_t *)ws; ws += (size_t)(NFLAT / 32) * 4;

  uint32_t fk[3][2];
  for (int i = 0; i < 3; ++i)
    tf2x32_host(0u, 42u, 0u, (uint32_t)i, &fk[i][0], &fk[i][1]);

  hipMemsetAsync(cursor, 0, (size_t)NN * 4, stream);
  prep_kernel<<<FILLB + CVTXB + CVTWB, 256, 0, stream>>>(
      src, dst, cursor, col2, x, xh, w0, w1, w2, lw, Wk0, Wk1, Wk2, WkL);

  // layer 0 (agg also generates m0)
  agg_kernel<<<NN / 4, 256, 0, stream>>>(xh, cursor, col2, agg, m0,
                                         fk[0][0], fk[0][1]);
  sage_gemm_f16<0><<<GBLK, 256, 0, stream>>>(agg, xh, Wk0, b0, m0, h1,
                                             nullptr, nullptr, nullptr);
  // layer 1 (agg also generates m1)
  agg_kernel<<<NN / 4, 256, 0, stream>>>(h1, cursor, col2, agg, m1,
                                         fk[1][0], fk[1][1]);
  sage_gemm_f16<0><<<GBLK, 256, 0, stream>>>(agg, h1, Wk1, b1, m1, h2,
                                             nullptr, nullptr, nullptr);
  // layer 2 fused with final linear: h3 lives only in LDS
  agg_kernel<<<NN / 4, 256, 0, stream>>>(h2, cursor, col2, agg, m2,
                                         fk[2][0], fk[2][1]);
  sage_gemm_f16<1><<<GBLK, 256, 128 * LDSW * 2, stream>>>(
      agg, h2, Wk2, b2, m2, nullptr, WkL, lb, out);
}